// Round 1
// baseline (622.419 us; speedup 1.0000x reference)
//
#include <hip/hip_runtime.h>

#define N_NODES 50000
#define N_EDGES 800000
#define IN_DIM  256
#define HC      256   // H*C
#define NHEAD   4
#define CDIM    64
#define NEG_SLOPE 0.2f
#define BN_EPS  1e-5f

// ---------------------------------------------------------------------------
// GEMM: x = feature[50000,256] @ W[256,256], fp32, 64x64 tile, 4x4 per thread
// ---------------------------------------------------------------------------
__global__ __launch_bounds__(256) void gemm_kernel(const float* __restrict__ A,
                                                   const float* __restrict__ B,
                                                   float* __restrict__ Cm)
{
    __shared__ float As[16][64];
    __shared__ float Bs[16][64];
    const int tid  = threadIdx.x;
    const int row0 = blockIdx.y * 64;
    const int col0 = blockIdx.x * 64;
    const int tx = tid & 15;        // 0..15 col group
    const int ty = tid >> 4;        // 0..15 row group
    // load indices
    const int ar = tid >> 2;        // 0..63 row within A tile
    const int ak = (tid & 3) << 2;  // 0,4,8,12 k within A tile
    const int bk = tid >> 4;        // 0..15 k within B tile
    const int bc = (tid & 15) << 2; // 0..60 col within B tile

    float acc[4][4] = {};
    for (int k0 = 0; k0 < 256; k0 += 16) {
        const int grow = row0 + ar;
        float4 av = make_float4(0.f, 0.f, 0.f, 0.f);
        if (grow < N_NODES)
            av = *(const float4*)(A + (size_t)grow * 256 + k0 + ak);
        As[ak + 0][ar] = av.x; As[ak + 1][ar] = av.y;
        As[ak + 2][ar] = av.z; As[ak + 3][ar] = av.w;
        const float4 bv = *(const float4*)(B + (size_t)(k0 + bk) * 256 + col0 + bc);
        *(float4*)&Bs[bk][bc] = bv;
        __syncthreads();
#pragma unroll
        for (int k = 0; k < 16; ++k) {
            const float4 a = *(const float4*)&As[k][ty * 4];
            const float4 b = *(const float4*)&Bs[k][tx * 4];
            acc[0][0] += a.x * b.x; acc[0][1] += a.x * b.y; acc[0][2] += a.x * b.z; acc[0][3] += a.x * b.w;
            acc[1][0] += a.y * b.x; acc[1][1] += a.y * b.y; acc[1][2] += a.y * b.z; acc[1][3] += a.y * b.w;
            acc[2][0] += a.z * b.x; acc[2][1] += a.z * b.y; acc[2][2] += a.z * b.z; acc[2][3] += a.z * b.w;
            acc[3][0] += a.w * b.x; acc[3][1] += a.w * b.y; acc[3][2] += a.w * b.z; acc[3][3] += a.w * b.w;
        }
        __syncthreads();
    }
#pragma unroll
    for (int i = 0; i < 4; ++i) {
        const int r = row0 + ty * 4 + i;
        if (r < N_NODES) {
            *(float4*)(Cm + (size_t)r * 256 + col0 + tx * 4) =
                make_float4(acc[i][0], acc[i][1], acc[i][2], acc[i][3]);
        }
    }
}

// ---------------------------------------------------------------------------
// Per-node attention logits: s[n,h] = <x[n,h,:], att_src[h,:]>, same for d.
// One wave per node; lane l owns channels [4l,4l+4); head = l>>4 (16 lanes/head).
// ---------------------------------------------------------------------------
__global__ __launch_bounds__(256) void logits_kernel(const float* __restrict__ x,
                                                     const float* __restrict__ att_src,
                                                     const float* __restrict__ att_dst,
                                                     float* __restrict__ s,
                                                     float* __restrict__ d)
{
    const int wid = threadIdx.x >> 6;
    const int lane = threadIdx.x & 63;
    const int n = blockIdx.x * 4 + wid;
    if (n >= N_NODES) return;
    const float4 xv = *(const float4*)(x + (size_t)n * 256 + lane * 4);
    const float4 as = *(const float4*)(att_src + lane * 4);
    const float4 ad = *(const float4*)(att_dst + lane * 4);
    float vs = xv.x * as.x + xv.y * as.y + xv.z * as.z + xv.w * as.w;
    float vd = xv.x * ad.x + xv.y * ad.y + xv.z * ad.z + xv.w * ad.w;
#pragma unroll
    for (int m = 8; m >= 1; m >>= 1) {
        vs += __shfl_xor(vs, m);
        vd += __shfl_xor(vd, m);
    }
    if ((lane & 15) == 0) {
        const int h = lane >> 4;
        s[n * 4 + h] = vs;
        d[n * 4 + h] = vd;
    }
}

// ---------------------------------------------------------------------------
// CSR build: histogram of dst, exclusive scan, scatter src indices
// ---------------------------------------------------------------------------
__global__ __launch_bounds__(256) void hist_kernel(const int* __restrict__ ei,
                                                   int* __restrict__ deg)
{
    const int e = blockIdx.x * 256 + threadIdx.x;
    if (e < N_EDGES) atomicAdd(&deg[ei[N_EDGES + e]], 1);
}

#define SCAN_ITEMS 49  // 1024*49 = 50176 >= 50000
__global__ __launch_bounds__(1024) void scan_kernel(const int* __restrict__ deg,
                                                    int* __restrict__ offsets,
                                                    int* __restrict__ cursor)
{
    __shared__ int part[1024];
    const int t = threadIdx.x;
    const int base = t * SCAN_ITEMS;
    int local = 0;
    for (int i = 0; i < SCAN_ITEMS; ++i) {
        const int idx = base + i;
        if (idx < N_NODES) local += deg[idx];
    }
    part[t] = local;
    __syncthreads();
    for (int off = 1; off < 1024; off <<= 1) {
        const int v = (t >= off) ? part[t - off] : 0;
        __syncthreads();
        part[t] += v;
        __syncthreads();
    }
    int run = part[t] - local;  // exclusive base for this thread's chunk
    for (int i = 0; i < SCAN_ITEMS; ++i) {
        const int idx = base + i;
        if (idx < N_NODES) {
            offsets[idx] = run;
            cursor[idx] = run;
            run += deg[idx];
        }
    }
    if (t == 1023) offsets[N_NODES] = part[1023];
}

__global__ __launch_bounds__(256) void scatter_kernel(const int* __restrict__ ei,
                                                      int* __restrict__ cursor,
                                                      int* __restrict__ csr_src)
{
    const int e = blockIdx.x * 256 + threadIdx.x;
    if (e < N_EDGES) {
        const int src = ei[e];
        const int dst = ei[N_EDGES + e];
        const int pos = atomicAdd(&cursor[dst], 1);
        csr_src[pos] = src;
    }
}

// ---------------------------------------------------------------------------
// Aggregate: softmax-weighted gather per dst node (self-loop included).
// One wave per node; lane l owns channels [4l,4l+4); head = l>>4.
// ---------------------------------------------------------------------------
__global__ __launch_bounds__(256) void aggregate_kernel(const float* __restrict__ x,
                                                        const float* __restrict__ s,
                                                        const float* __restrict__ d,
                                                        const int* __restrict__ offsets,
                                                        const int* __restrict__ csr_src,
                                                        float* __restrict__ out)
{
    const int wid = threadIdx.x >> 6;
    const int lane = threadIdx.x & 63;
    const int n = blockIdx.x * 4 + wid;
    if (n >= N_NODES) return;
    const int h = lane >> 4;
    const float dn = d[n * 4 + h];
    const float sn = s[n * 4 + h];
    const float4 xr = *(const float4*)(x + (size_t)n * 256 + lane * 4);
    float eself = sn + dn;
    eself = eself >= 0.f ? eself : NEG_SLOPE * eself;
    const float pself = __expf(eself);
    float den = pself;
    float4 acc = make_float4(pself * xr.x, pself * xr.y, pself * xr.z, pself * xr.w);
    const int e0 = offsets[n];
    const int e1 = offsets[n + 1];
    for (int e = e0; e < e1; ++e) {
        const int src = csr_src[e];
        float ee = s[src * 4 + h] + dn;
        ee = ee >= 0.f ? ee : NEG_SLOPE * ee;
        const float pe = __expf(ee);
        const float4 xs = *(const float4*)(x + (size_t)src * 256 + lane * 4);
        acc.x += pe * xs.x; acc.y += pe * xs.y;
        acc.z += pe * xs.z; acc.w += pe * xs.w;
        den += pe;
    }
    const float inv = 1.0f / den;
    *(float4*)(out + (size_t)n * 256 + lane * 4) =
        make_float4(acc.x * inv, acc.y * inv, acc.z * inv, acc.w * inv);
}

// ---------------------------------------------------------------------------
// BatchNorm stats (bias cancels in (h - mean), so ignored)
// ---------------------------------------------------------------------------
__global__ __launch_bounds__(256) void bn_stats_kernel(const float* __restrict__ out,
                                                       float* __restrict__ gsum,
                                                       float* __restrict__ gsumsq)
{
    const int c = threadIdx.x;
    float sum = 0.f, sq = 0.f;
    for (int r = blockIdx.x; r < N_NODES; r += gridDim.x) {
        const float v = out[(size_t)r * 256 + c];
        sum += v;
        sq += v * v;
    }
    atomicAdd(&gsum[c], sum);
    atomicAdd(&gsumsq[c], sq);
}

__global__ __launch_bounds__(256) void bn_final_kernel(const float* __restrict__ gsum,
                                                       const float* __restrict__ gsumsq,
                                                       const float* __restrict__ gamma,
                                                       float* __restrict__ meanArr,
                                                       float* __restrict__ scaleArr)
{
    const int c = threadIdx.x;
    const float m = gsum[c] * (1.0f / N_NODES);
    const float var = gsumsq[c] * (1.0f / N_NODES) - m * m;
    meanArr[c] = m;
    scaleArr[c] = gamma[c] * rsqrtf(var + BN_EPS);
}

// ---------------------------------------------------------------------------
// Finalize: normalize + ELU + residual, in place on d_out
// ---------------------------------------------------------------------------
__global__ __launch_bounds__(256) void finalize_kernel(const float* __restrict__ feature,
                                                       const float* __restrict__ meanArr,
                                                       const float* __restrict__ scaleArr,
                                                       const float* __restrict__ beta,
                                                       float* __restrict__ out)
{
    const size_t i = (size_t)blockIdx.x * 256 + threadIdx.x;  // float4 index
    const int c4 = (int)(i & 63);
    float4 v = ((const float4*)out)[i];
    const float4 m = ((const float4*)meanArr)[c4];
    const float4 sc = ((const float4*)scaleArr)[c4];
    const float4 b = ((const float4*)beta)[c4];
    const float4 f = ((const float4*)feature)[i];
    float r0 = (v.x - m.x) * sc.x + b.x;
    float r1 = (v.y - m.y) * sc.y + b.y;
    float r2 = (v.z - m.z) * sc.z + b.z;
    float r3 = (v.w - m.w) * sc.w + b.w;
    r0 = r0 > 0.f ? r0 : expm1f(r0);
    r1 = r1 > 0.f ? r1 : expm1f(r1);
    r2 = r2 > 0.f ? r2 : expm1f(r2);
    r3 = r3 > 0.f ? r3 : expm1f(r3);
    ((float4*)out)[i] = make_float4(r0 + f.x, r1 + f.y, r2 + f.z, r3 + f.w);
}

// ---------------------------------------------------------------------------
extern "C" void kernel_launch(void* const* d_in, const int* in_sizes, int n_in,
                              void* d_out, int out_size, void* d_ws, size_t ws_size,
                              hipStream_t stream)
{
    const float* feature = (const float*)d_in[0];
    const int*   ei      = (const int*)d_in[1];
    const float* W       = (const float*)d_in[2];
    const float* att_src = (const float*)d_in[3];
    const float* att_dst = (const float*)d_in[4];
    // d_in[5] = bias: cancels inside batchnorm, unused
    const float* gamma   = (const float*)d_in[6];
    const float* beta    = (const float*)d_in[7];
    float* out = (float*)d_out;

    char* w = (char*)d_ws;
    auto carve = [&](size_t bytes) {
        char* p = w;
        w += (bytes + 255) & ~(size_t)255;
        return p;
    };
    float* x        = (float*)carve((size_t)N_NODES * 256 * 4);
    float* s        = (float*)carve((size_t)N_NODES * 4 * 4);
    float* dv       = (float*)carve((size_t)N_NODES * 4 * 4);
    int*   deg      = (int*)carve((size_t)N_NODES * 4);
    int*   offsets  = (int*)carve((size_t)(N_NODES + 1) * 4);
    int*   cursor   = (int*)carve((size_t)N_NODES * 4);
    int*   csr_src  = (int*)carve((size_t)N_EDGES * 4);
    float* gsum     = (float*)carve(256 * 4);
    float* gsumsq   = (float*)carve(256 * 4);
    float* meanArr  = (float*)carve(256 * 4);
    float* scaleArr = (float*)carve(256 * 4);

    hipMemsetAsync(deg, 0, (size_t)N_NODES * 4, stream);
    hipMemsetAsync(gsum, 0, 256 * 4, stream);
    hipMemsetAsync(gsumsq, 0, 256 * 4, stream);

    gemm_kernel<<<dim3(4, 782), 256, 0, stream>>>(feature, W, x);
    logits_kernel<<<12500, 256, 0, stream>>>(x, att_src, att_dst, s, dv);
    hist_kernel<<<3125, 256, 0, stream>>>(ei, deg);
    scan_kernel<<<1, 1024, 0, stream>>>(deg, offsets, cursor);
    scatter_kernel<<<3125, 256, 0, stream>>>(ei, cursor, csr_src);
    aggregate_kernel<<<12500, 256, 0, stream>>>(x, s, dv, offsets, csr_src, out);
    bn_stats_kernel<<<256, 256, 0, stream>>>(out, gsum, gsumsq);
    bn_final_kernel<<<1, 256, 0, stream>>>(gsum, gsumsq, gamma, meanArr, scaleArr);
    finalize_kernel<<<12500, 256, 0, stream>>>(feature, meanArr, scaleArr, beta, out);
}

// Round 2
// 488.093 us; speedup vs baseline: 1.2752x; 1.2752x over previous
//
#include <hip/hip_runtime.h>

#define N_NODES 50000
#define N_EDGES 800000
#define NEG_SLOPE 0.2f
#define BN_EPS  1e-5f

typedef short bf16x8 __attribute__((ext_vector_type(8)));
typedef float floatx4 __attribute__((ext_vector_type(4)));

__device__ inline ushort f2bf(float f) {
    union { float f; unsigned u; } v; v.f = f;
    unsigned r = v.u + 0x7fff + ((v.u >> 16) & 1);
    return (ushort)(r >> 16);
}
__device__ inline float bf2f(ushort h) {
    union { unsigned u; float f; } v; v.u = ((unsigned)h) << 16;
    return v.f;
}

// ---------------------------------------------------------------------------
// Convert: feature fp32 -> bf16 (featb), W fp32 [K][N] -> Wt bf16 [N][K]
// ---------------------------------------------------------------------------
#define FEAT_CONV_BLOCKS 12500   // 50000*256/4/256
__global__ __launch_bounds__(256) void convert_kernel(const float* __restrict__ feature,
                                                      const float* __restrict__ W,
                                                      ushort* __restrict__ featb,
                                                      ushort* __restrict__ Wtb)
{
    const int b = blockIdx.x;
    if (b < FEAT_CONV_BLOCKS) {
        const size_t i = (size_t)b * 256 + threadIdx.x;  // float4 index
        const float4 v = ((const float4*)feature)[i];
        ushort4 o;
        o.x = f2bf(v.x); o.y = f2bf(v.y); o.z = f2bf(v.z); o.w = f2bf(v.w);
        ((ushort4*)featb)[i] = o;
    } else {
        const int n = b - FEAT_CONV_BLOCKS;  // 0..255 output col
        const int k = threadIdx.x;
        Wtb[n * 256 + k] = f2bf(W[k * 256 + n]);
    }
}

// ---------------------------------------------------------------------------
// MFMA GEMM: xb[M,256] = bf16( featb[M,256] @ W ), W given as Wt bf16 [N][K].
// 128x128 tile / block, 4 waves each 64x64 via 4x4 grid of 16x16x32 MFMAs.
// Epilogue ALSO computes per-node attention logits s,d (each wave's 64 cols
// are exactly one head) via 16-lane shuffle reduction.
// ---------------------------------------------------------------------------
#define LDSTRIDE 40  // 32 + 8 pad: 2-way max bank aliasing (free)
__global__ __launch_bounds__(256) void gemm_kernel(const ushort* __restrict__ A,
                                                   const ushort* __restrict__ Bt,
                                                   const float* __restrict__ att_src,
                                                   const float* __restrict__ att_dst,
                                                   ushort* __restrict__ Xb,
                                                   float* __restrict__ s,
                                                   float* __restrict__ d)
{
    __shared__ ushort As[128 * LDSTRIDE];
    __shared__ ushort Bs[128 * LDSTRIDE];
    const int tid = threadIdx.x;
    const int lane = tid & 63;
    const int wid = tid >> 6;
    const int wm = wid & 1, wn = wid >> 1;
    const int row0 = blockIdx.y * 128;
    const int col0 = blockIdx.x * 128;

    floatx4 acc[4][4] = {};  // [mi][ni]

    const int lr = tid >> 2;        // 0..63 (row pair base)
    const int lk = (tid & 3) * 8;   // 0,8,16,24 (k elem offset)

    for (int k0 = 0; k0 < 256; k0 += 32) {
#pragma unroll
        for (int r = 0; r < 2; ++r) {
            const int row = lr + r * 64;
            const int grow = row0 + row;
            ulonglong2 av = {0ull, 0ull};
            if (grow < N_NODES)
                av = *(const ulonglong2*)(A + (size_t)grow * 256 + k0 + lk);
            *(ulonglong2*)(As + row * LDSTRIDE + lk) = av;
            const ulonglong2 bv = *(const ulonglong2*)(Bt + (size_t)(col0 + row) * 256 + k0 + lk);
            *(ulonglong2*)(Bs + row * LDSTRIDE + lk) = bv;
        }
        __syncthreads();
        const int quad = lane >> 4;
        const int l16 = lane & 15;
        bf16x8 afrag[4], bfrag[4];
#pragma unroll
        for (int mi = 0; mi < 4; ++mi)
            afrag[mi] = *(const bf16x8*)(As + (wm * 64 + mi * 16 + l16) * LDSTRIDE + quad * 8);
#pragma unroll
        for (int ni = 0; ni < 4; ++ni)
            bfrag[ni] = *(const bf16x8*)(Bs + (wn * 64 + ni * 16 + l16) * LDSTRIDE + quad * 8);
#pragma unroll
        for (int mi = 0; mi < 4; ++mi)
#pragma unroll
            for (int ni = 0; ni < 4; ++ni)
                acc[mi][ni] = __builtin_amdgcn_mfma_f32_16x16x32_bf16(afrag[mi], bfrag[ni], acc[mi][ni], 0, 0, 0);
        __syncthreads();
    }

    const int quad = lane >> 4;
    const int l16 = lane & 15;
    const int head = (col0 + wn * 64) >> 6;  // wave's 64 cols = one head
    float as_l[4], ad_l[4];
#pragma unroll
    for (int ni = 0; ni < 4; ++ni) {
        const int ch = head * 64 + ni * 16 + l16;
        as_l[ni] = att_src[ch];
        ad_l[ni] = att_dst[ch];
    }
#pragma unroll
    for (int mi = 0; mi < 4; ++mi) {
#pragma unroll
        for (int r = 0; r < 4; ++r) {
            const int grow = row0 + wm * 64 + mi * 16 + quad * 4 + r;
            const bool ok = grow < N_NODES;
            float vs = 0.f, vd = 0.f;
#pragma unroll
            for (int ni = 0; ni < 4; ++ni) {
                const float v = acc[mi][ni][r];
                vs += v * as_l[ni];
                vd += v * ad_l[ni];
                if (ok)
                    Xb[(size_t)grow * 256 + col0 + wn * 64 + ni * 16 + l16] = f2bf(v);
            }
#pragma unroll
            for (int m = 8; m >= 1; m >>= 1) {
                vs += __shfl_xor(vs, m);
                vd += __shfl_xor(vd, m);
            }
            if (l16 == 0 && ok) {
                s[grow * 4 + head] = vs;
                d[grow * 4 + head] = vd;
            }
        }
    }
}

// ---------------------------------------------------------------------------
// CSR build: histogram of dst, exclusive scan, scatter src indices
// ---------------------------------------------------------------------------
__global__ __launch_bounds__(256) void hist_kernel(const int* __restrict__ ei,
                                                   int* __restrict__ deg)
{
    const int e = blockIdx.x * 256 + threadIdx.x;
    if (e < N_EDGES) atomicAdd(&deg[ei[N_EDGES + e]], 1);
}

#define SCAN_ITEMS 49  // 1024*49 = 50176 >= 50000
__global__ __launch_bounds__(1024) void scan_kernel(const int* __restrict__ deg,
                                                    int* __restrict__ offsets,
                                                    int* __restrict__ cursor)
{
    __shared__ int part[1024];
    const int t = threadIdx.x;
    const int base = t * SCAN_ITEMS;
    int local = 0;
    for (int i = 0; i < SCAN_ITEMS; ++i) {
        const int idx = base + i;
        if (idx < N_NODES) local += deg[idx];
    }
    part[t] = local;
    __syncthreads();
    for (int off = 1; off < 1024; off <<= 1) {
        const int v = (t >= off) ? part[t - off] : 0;
        __syncthreads();
        part[t] += v;
        __syncthreads();
    }
    int run = part[t] - local;
    for (int i = 0; i < SCAN_ITEMS; ++i) {
        const int idx = base + i;
        if (idx < N_NODES) {
            offsets[idx] = run;
            cursor[idx] = run;
            run += deg[idx];
        }
    }
    if (t == 1023) offsets[N_NODES] = part[1023];
}

__global__ __launch_bounds__(256) void scatter_kernel(const int* __restrict__ ei,
                                                      int* __restrict__ cursor,
                                                      int* __restrict__ csr_src)
{
    const int e = blockIdx.x * 256 + threadIdx.x;
    if (e < N_EDGES) {
        const int src = ei[e];
        const int dst = ei[N_EDGES + e];
        const int pos = atomicAdd(&cursor[dst], 1);
        csr_src[pos] = src;
    }
}

// ---------------------------------------------------------------------------
// Aggregate: softmax-weighted gather per dst node (self-loop included).
// One wave per node; lane l owns channels [4l,4l+4) bf16; head = l>>4.
// Edge loop unrolled x4 for gather ILP.
// ---------------------------------------------------------------------------
__global__ __launch_bounds__(256) void aggregate_kernel(const ushort* __restrict__ xb,
                                                        const float* __restrict__ s,
                                                        const float* __restrict__ d,
                                                        const int* __restrict__ offsets,
                                                        const int* __restrict__ csr_src,
                                                        float* __restrict__ out)
{
    const int wid = threadIdx.x >> 6;
    const int lane = threadIdx.x & 63;
    const int n = blockIdx.x * 4 + wid;
    if (n >= N_NODES) return;
    const int h = lane >> 4;
    const float dn = d[n * 4 + h];
    const float sn = s[n * 4 + h];
    const ushort4 xr = *(const ushort4*)(xb + (size_t)n * 256 + lane * 4);
    float eself = sn + dn;
    eself = eself >= 0.f ? eself : NEG_SLOPE * eself;
    const float pself = __expf(eself);
    float den = pself;
    float a0 = pself * bf2f(xr.x), a1 = pself * bf2f(xr.y);
    float a2 = pself * bf2f(xr.z), a3 = pself * bf2f(xr.w);
    const int e0 = offsets[n];
    const int e1 = offsets[n + 1];
    int e = e0;
    for (; e + 4 <= e1; e += 4) {
        const int s0 = csr_src[e];
        const int s1 = csr_src[e + 1];
        const int s2 = csr_src[e + 2];
        const int s3 = csr_src[e + 3];
        float l0 = s[s0 * 4 + h] + dn;
        float l1 = s[s1 * 4 + h] + dn;
        float l2 = s[s2 * 4 + h] + dn;
        float l3 = s[s3 * 4 + h] + dn;
        const ushort4 x0 = *(const ushort4*)(xb + (size_t)s0 * 256 + lane * 4);
        const ushort4 x1 = *(const ushort4*)(xb + (size_t)s1 * 256 + lane * 4);
        const ushort4 x2 = *(const ushort4*)(xb + (size_t)s2 * 256 + lane * 4);
        const ushort4 x3 = *(const ushort4*)(xb + (size_t)s3 * 256 + lane * 4);
        l0 = l0 >= 0.f ? l0 : NEG_SLOPE * l0;
        l1 = l1 >= 0.f ? l1 : NEG_SLOPE * l1;
        l2 = l2 >= 0.f ? l2 : NEG_SLOPE * l2;
        l3 = l3 >= 0.f ? l3 : NEG_SLOPE * l3;
        const float p0 = __expf(l0), p1 = __expf(l1);
        const float p2 = __expf(l2), p3 = __expf(l3);
        den += p0 + p1 + p2 + p3;
        a0 += p0 * bf2f(x0.x) + p1 * bf2f(x1.x) + p2 * bf2f(x2.x) + p3 * bf2f(x3.x);
        a1 += p0 * bf2f(x0.y) + p1 * bf2f(x1.y) + p2 * bf2f(x2.y) + p3 * bf2f(x3.y);
        a2 += p0 * bf2f(x0.z) + p1 * bf2f(x1.z) + p2 * bf2f(x2.z) + p3 * bf2f(x3.z);
        a3 += p0 * bf2f(x0.w) + p1 * bf2f(x1.w) + p2 * bf2f(x2.w) + p3 * bf2f(x3.w);
    }
    for (; e < e1; ++e) {
        const int src = csr_src[e];
        float ee = s[src * 4 + h] + dn;
        ee = ee >= 0.f ? ee : NEG_SLOPE * ee;
        const float pe = __expf(ee);
        const ushort4 xs = *(const ushort4*)(xb + (size_t)src * 256 + lane * 4);
        a0 += pe * bf2f(xs.x); a1 += pe * bf2f(xs.y);
        a2 += pe * bf2f(xs.z); a3 += pe * bf2f(xs.w);
        den += pe;
    }
    const float inv = 1.0f / den;
    *(float4*)(out + (size_t)n * 256 + lane * 4) =
        make_float4(a0 * inv, a1 * inv, a2 * inv, a3 * inv);
}

// ---------------------------------------------------------------------------
// BatchNorm stats (bias cancels in (h - mean), so ignored)
// ---------------------------------------------------------------------------
__global__ __launch_bounds__(256) void bn_stats_kernel(const float* __restrict__ out,
                                                       float* __restrict__ gsum,
                                                       float* __restrict__ gsumsq)
{
    const int c = threadIdx.x;
    float sum = 0.f, sq = 0.f;
    for (int r = blockIdx.x; r < N_NODES; r += gridDim.x) {
        const float v = out[(size_t)r * 256 + c];
        sum += v;
        sq += v * v;
    }
    atomicAdd(&gsum[c], sum);
    atomicAdd(&gsumsq[c], sq);
}

__global__ __launch_bounds__(256) void bn_final_kernel(const float* __restrict__ gsum,
                                                       const float* __restrict__ gsumsq,
                                                       const float* __restrict__ gamma,
                                                       float* __restrict__ meanArr,
                                                       float* __restrict__ scaleArr)
{
    const int c = threadIdx.x;
    const float m = gsum[c] * (1.0f / N_NODES);
    const float var = gsumsq[c] * (1.0f / N_NODES) - m * m;
    meanArr[c] = m;
    scaleArr[c] = gamma[c] * rsqrtf(var + BN_EPS);
}

// ---------------------------------------------------------------------------
// Finalize: normalize + ELU + residual, in place on d_out
// ---------------------------------------------------------------------------
__global__ __launch_bounds__(256) void finalize_kernel(const float* __restrict__ feature,
                                                       const float* __restrict__ meanArr,
                                                       const float* __restrict__ scaleArr,
                                                       const float* __restrict__ beta,
                                                       float* __restrict__ out)
{
    const size_t i = (size_t)blockIdx.x * 256 + threadIdx.x;  // float4 index
    const int c4 = (int)(i & 63);
    float4 v = ((const float4*)out)[i];
    const float4 m = ((const float4*)meanArr)[c4];
    const float4 sc = ((const float4*)scaleArr)[c4];
    const float4 b = ((const float4*)beta)[c4];
    const float4 f = ((const float4*)feature)[i];
    float r0 = (v.x - m.x) * sc.x + b.x;
    float r1 = (v.y - m.y) * sc.y + b.y;
    float r2 = (v.z - m.z) * sc.z + b.z;
    float r3 = (v.w - m.w) * sc.w + b.w;
    r0 = r0 > 0.f ? r0 : expm1f(r0);
    r1 = r1 > 0.f ? r1 : expm1f(r1);
    r2 = r2 > 0.f ? r2 : expm1f(r2);
    r3 = r3 > 0.f ? r3 : expm1f(r3);
    ((float4*)out)[i] = make_float4(r0 + f.x, r1 + f.y, r2 + f.z, r3 + f.w);
}

// ---------------------------------------------------------------------------
extern "C" void kernel_launch(void* const* d_in, const int* in_sizes, int n_in,
                              void* d_out, int out_size, void* d_ws, size_t ws_size,
                              hipStream_t stream)
{
    const float* feature = (const float*)d_in[0];
    const int*   ei      = (const int*)d_in[1];
    const float* W       = (const float*)d_in[2];
    const float* att_src = (const float*)d_in[3];
    const float* att_dst = (const float*)d_in[4];
    // d_in[5] = bias: cancels inside batchnorm, unused
    const float* gamma   = (const float*)d_in[6];
    const float* beta    = (const float*)d_in[7];
    float* out = (float*)d_out;

    char* w = (char*)d_ws;
    auto carve = [&](size_t bytes) {
        char* p = w;
        w += (bytes + 255) & ~(size_t)255;
        return p;
    };
    ushort* featb   = (ushort*)carve((size_t)N_NODES * 256 * 2);
    ushort* Wtb     = (ushort*)carve((size_t)256 * 256 * 2);
    ushort* xb      = (ushort*)carve((size_t)N_NODES * 256 * 2);
    float* s        = (float*)carve((size_t)N_NODES * 4 * 4);
    float* dv       = (float*)carve((size_t)N_NODES * 4 * 4);
    int*   deg      = (int*)carve((size_t)N_NODES * 4);
    int*   offsets  = (int*)carve((size_t)(N_NODES + 1) * 4);
    int*   cursor   = (int*)carve((size_t)N_NODES * 4);
    int*   csr_src  = (int*)carve((size_t)N_EDGES * 4);
    float* gsum     = (float*)carve(256 * 4);
    float* gsumsq   = (float*)carve(256 * 4);
    float* meanArr  = (float*)carve(256 * 4);
    float* scaleArr = (float*)carve(256 * 4);

    hipMemsetAsync(deg, 0, (size_t)N_NODES * 4, stream);
    hipMemsetAsync(gsum, 0, 256 * 4, stream);
    hipMemsetAsync(gsumsq, 0, 256 * 4, stream);

    convert_kernel<<<FEAT_CONV_BLOCKS + 256, 256, 0, stream>>>(feature, W, featb, Wtb);
    hist_kernel<<<3125, 256, 0, stream>>>(ei, deg);
    scan_kernel<<<1, 1024, 0, stream>>>(deg, offsets, cursor);
    scatter_kernel<<<3125, 256, 0, stream>>>(ei, cursor, csr_src);
    gemm_kernel<<<dim3(2, 391), 256, 0, stream>>>(featb, Wtb, att_src, att_dst, xb, s, dv);
    aggregate_kernel<<<12500, 256, 0, stream>>>(xb, s, dv, offsets, csr_src, out);
    bn_stats_kernel<<<256, 256, 0, stream>>>(out, gsum, gsumsq);
    bn_final_kernel<<<1, 256, 0, stream>>>(gsum, gsumsq, gamma, meanArr, scaleArr);
    finalize_kernel<<<12500, 256, 0, stream>>>(feature, meanArr, scaleArr, beta, out);
}

// Round 3
// 367.247 us; speedup vs baseline: 1.6948x; 1.3291x over previous
//
#include <hip/hip_runtime.h>

#define N_NODES 50000
#define N_EDGES 800000
#define NEG_SLOPE 0.2f
#define BN_EPS  1e-5f

typedef short bf16x8 __attribute__((ext_vector_type(8)));
typedef float floatx4 __attribute__((ext_vector_type(4)));

__device__ inline ushort f2bf(float f) {
    union { float f; unsigned u; } v; v.f = f;
    unsigned r = v.u + 0x7fff + ((v.u >> 16) & 1);
    return (ushort)(r >> 16);
}
__device__ inline float bf2f(ushort h) {
    union { unsigned u; float f; } v; v.u = ((unsigned)h) << 16;
    return v.f;
}

// ---------------------------------------------------------------------------
// Convert + histogram fused:
//   blocks [0, FEAT_CONV_BLOCKS)             : feature fp32 -> bf16
//   blocks [FEAT_CONV_BLOCKS, +256)          : W fp32 [K][N] -> Wt bf16 [N][K]
//   blocks [FEAT_CONV_BLOCKS+256, +3125)     : histogram of dst into deg
// deg is zeroed by a hipMemsetAsync before this kernel.
// ---------------------------------------------------------------------------
#define FEAT_CONV_BLOCKS 12500   // 50000*256/4/256
#define HIST_BLOCKS 3125
__global__ __launch_bounds__(256) void convert_hist_kernel(const float* __restrict__ feature,
                                                           const float* __restrict__ W,
                                                           const int* __restrict__ ei,
                                                           ushort* __restrict__ featb,
                                                           ushort* __restrict__ Wtb,
                                                           int* __restrict__ deg)
{
    const int b = blockIdx.x;
    if (b < FEAT_CONV_BLOCKS) {
        const size_t i = (size_t)b * 256 + threadIdx.x;  // float4 index
        const float4 v = ((const float4*)feature)[i];
        ushort4 o;
        o.x = f2bf(v.x); o.y = f2bf(v.y); o.z = f2bf(v.z); o.w = f2bf(v.w);
        ((ushort4*)featb)[i] = o;
    } else if (b < FEAT_CONV_BLOCKS + 256) {
        const int n = b - FEAT_CONV_BLOCKS;  // 0..255 output col
        const int k = threadIdx.x;
        Wtb[n * 256 + k] = f2bf(W[k * 256 + n]);
    } else {
        const int e = (b - FEAT_CONV_BLOCKS - 256) * 256 + threadIdx.x;
        if (e < N_EDGES) atomicAdd(&deg[ei[N_EDGES + e]], 1);
    }
}

// ---------------------------------------------------------------------------
// Multi-block exclusive scan of deg[50000] -> offsets, cursor
// ---------------------------------------------------------------------------
#define SCAN_BLOCKS 196  // 196*256 = 50176 >= 50000
__global__ __launch_bounds__(256) void scan1_kernel(const int* __restrict__ deg,
                                                    int* __restrict__ offsets,
                                                    int* __restrict__ blocksum)
{
    __shared__ int sm[256];
    const int t = threadIdx.x;
    const int i = blockIdx.x * 256 + t;
    const int v = (i < N_NODES) ? deg[i] : 0;
    sm[t] = v;
    __syncthreads();
#pragma unroll
    for (int off = 1; off < 256; off <<= 1) {
        const int u = (t >= off) ? sm[t - off] : 0;
        __syncthreads();
        sm[t] += u;
        __syncthreads();
    }
    if (i < N_NODES) offsets[i] = sm[t] - v;  // block-local exclusive
    if (t == 255) blocksum[blockIdx.x] = sm[255];
}

__global__ __launch_bounds__(256) void scan2_kernel(const int* __restrict__ blocksum,
                                                    int* __restrict__ blockbase,
                                                    float* __restrict__ gsum,
                                                    float* __restrict__ gsumsq)
{
    __shared__ int sm[256];
    const int t = threadIdx.x;
    const int v = (t < SCAN_BLOCKS) ? blocksum[t] : 0;
    sm[t] = v;
    __syncthreads();
#pragma unroll
    for (int off = 1; off < 256; off <<= 1) {
        const int u = (t >= off) ? sm[t - off] : 0;
        __syncthreads();
        sm[t] += u;
        __syncthreads();
    }
    if (t < SCAN_BLOCKS) blockbase[t] = sm[t] - v;
    // piggyback: zero BN accumulators (runs before bn_stats)
    gsum[t] = 0.f;
    gsumsq[t] = 0.f;
}

__global__ __launch_bounds__(256) void scan3_kernel(const int* __restrict__ blockbase,
                                                    int* __restrict__ offsets,
                                                    int* __restrict__ cursor)
{
    const int i = blockIdx.x * 256 + threadIdx.x;
    if (i < N_NODES) {
        const int o = offsets[i] + blockbase[blockIdx.x];
        offsets[i] = o;
        cursor[i] = o;
    }
    if (i == 0) offsets[N_NODES] = N_EDGES;
}

__global__ __launch_bounds__(256) void scatter_kernel(const int* __restrict__ ei,
                                                      int* __restrict__ cursor,
                                                      int* __restrict__ csr_src)
{
    const int e = blockIdx.x * 256 + threadIdx.x;
    if (e < N_EDGES) {
        const int src = ei[e];
        const int dst = ei[N_EDGES + e];
        const int pos = atomicAdd(&cursor[dst], 1);
        csr_src[pos] = src;
    }
}

// ---------------------------------------------------------------------------
// MFMA GEMM: xb[M,256] = bf16( featb[M,256] @ W ), W given as Wt bf16 [N][K].
// 128x128 tile / block, 4 waves each 64x64 via 4x4 grid of 16x16x32 MFMAs.
// Epilogue ALSO computes per-node attention logits s,d (each wave's 64 cols
// are exactly one head) via 16-lane shuffle reduction.
// ---------------------------------------------------------------------------
#define LDSTRIDE 40  // 32 + 8 pad: 2-way max bank aliasing (free)
__global__ __launch_bounds__(256) void gemm_kernel(const ushort* __restrict__ A,
                                                   const ushort* __restrict__ Bt,
                                                   const float* __restrict__ att_src,
                                                   const float* __restrict__ att_dst,
                                                   ushort* __restrict__ Xb,
                                                   float* __restrict__ s,
                                                   float* __restrict__ d)
{
    __shared__ ushort As[128 * LDSTRIDE];
    __shared__ ushort Bs[128 * LDSTRIDE];
    const int tid = threadIdx.x;
    const int lane = tid & 63;
    const int wid = tid >> 6;
    const int wm = wid & 1, wn = wid >> 1;
    const int row0 = blockIdx.y * 128;
    const int col0 = blockIdx.x * 128;

    floatx4 acc[4][4] = {};  // [mi][ni]

    const int lr = tid >> 2;        // 0..63 (row pair base)
    const int lk = (tid & 3) * 8;   // 0,8,16,24 (k elem offset)

    for (int k0 = 0; k0 < 256; k0 += 32) {
#pragma unroll
        for (int r = 0; r < 2; ++r) {
            const int row = lr + r * 64;
            const int grow = row0 + row;
            ulonglong2 av = {0ull, 0ull};
            if (grow < N_NODES)
                av = *(const ulonglong2*)(A + (size_t)grow * 256 + k0 + lk);
            *(ulonglong2*)(As + row * LDSTRIDE + lk) = av;
            const ulonglong2 bv = *(const ulonglong2*)(Bt + (size_t)(col0 + row) * 256 + k0 + lk);
            *(ulonglong2*)(Bs + row * LDSTRIDE + lk) = bv;
        }
        __syncthreads();
        const int quad = lane >> 4;
        const int l16 = lane & 15;
        bf16x8 afrag[4], bfrag[4];
#pragma unroll
        for (int mi = 0; mi < 4; ++mi)
            afrag[mi] = *(const bf16x8*)(As + (wm * 64 + mi * 16 + l16) * LDSTRIDE + quad * 8);
#pragma unroll
        for (int ni = 0; ni < 4; ++ni)
            bfrag[ni] = *(const bf16x8*)(Bs + (wn * 64 + ni * 16 + l16) * LDSTRIDE + quad * 8);
#pragma unroll
        for (int mi = 0; mi < 4; ++mi)
#pragma unroll
            for (int ni = 0; ni < 4; ++ni)
                acc[mi][ni] = __builtin_amdgcn_mfma_f32_16x16x32_bf16(afrag[mi], bfrag[ni], acc[mi][ni], 0, 0, 0);
        __syncthreads();
    }

    const int quad = lane >> 4;
    const int l16 = lane & 15;
    const int head = (col0 + wn * 64) >> 6;  // wave's 64 cols = one head
    float as_l[4], ad_l[4];
#pragma unroll
    for (int ni = 0; ni < 4; ++ni) {
        const int ch = head * 64 + ni * 16 + l16;
        as_l[ni] = att_src[ch];
        ad_l[ni] = att_dst[ch];
    }
#pragma unroll
    for (int mi = 0; mi < 4; ++mi) {
#pragma unroll
        for (int r = 0; r < 4; ++r) {
            const int grow = row0 + wm * 64 + mi * 16 + quad * 4 + r;
            const bool ok = grow < N_NODES;
            float vs = 0.f, vd = 0.f;
#pragma unroll
            for (int ni = 0; ni < 4; ++ni) {
                const float v = acc[mi][ni][r];
                vs += v * as_l[ni];
                vd += v * ad_l[ni];
                if (ok)
                    Xb[(size_t)grow * 256 + col0 + wn * 64 + ni * 16 + l16] = f2bf(v);
            }
#pragma unroll
            for (int m = 8; m >= 1; m >>= 1) {
                vs += __shfl_xor(vs, m);
                vd += __shfl_xor(vd, m);
            }
            if (l16 == 0 && ok) {
                s[grow * 4 + head] = vs;
                d[grow * 4 + head] = vd;
            }
        }
    }
}

// ---------------------------------------------------------------------------
// Aggregate: softmax-weighted gather per dst node (self-loop included).
// One wave per node; lane l owns channels [4l,4l+4) bf16; head = l>>4.
// Edge loop unrolled x4 for gather ILP. Output h in bf16 (pre-BN).
// ---------------------------------------------------------------------------
__global__ __launch_bounds__(256) void aggregate_kernel(const ushort* __restrict__ xb,
                                                        const float* __restrict__ s,
                                                        const float* __restrict__ d,
                                                        const int* __restrict__ offsets,
                                                        const int* __restrict__ csr_src,
                                                        ushort* __restrict__ hagg)
{
    const int wid = threadIdx.x >> 6;
    const int lane = threadIdx.x & 63;
    const int n = blockIdx.x * 4 + wid;
    if (n >= N_NODES) return;
    const int h = lane >> 4;
    const float dn = d[n * 4 + h];
    const float sn = s[n * 4 + h];
    const ushort4 xr = *(const ushort4*)(xb + (size_t)n * 256 + lane * 4);
    float eself = sn + dn;
    eself = eself >= 0.f ? eself : NEG_SLOPE * eself;
    const float pself = __expf(eself);
    float den = pself;
    float a0 = pself * bf2f(xr.x), a1 = pself * bf2f(xr.y);
    float a2 = pself * bf2f(xr.z), a3 = pself * bf2f(xr.w);
    const int e0 = offsets[n];
    const int e1 = offsets[n + 1];
    int e = e0;
    for (; e + 4 <= e1; e += 4) {
        const int s0 = csr_src[e];
        const int s1 = csr_src[e + 1];
        const int s2 = csr_src[e + 2];
        const int s3 = csr_src[e + 3];
        float l0 = s[s0 * 4 + h] + dn;
        float l1 = s[s1 * 4 + h] + dn;
        float l2 = s[s2 * 4 + h] + dn;
        float l3 = s[s3 * 4 + h] + dn;
        const ushort4 x0 = *(const ushort4*)(xb + (size_t)s0 * 256 + lane * 4);
        const ushort4 x1 = *(const ushort4*)(xb + (size_t)s1 * 256 + lane * 4);
        const ushort4 x2 = *(const ushort4*)(xb + (size_t)s2 * 256 + lane * 4);
        const ushort4 x3 = *(const ushort4*)(xb + (size_t)s3 * 256 + lane * 4);
        l0 = l0 >= 0.f ? l0 : NEG_SLOPE * l0;
        l1 = l1 >= 0.f ? l1 : NEG_SLOPE * l1;
        l2 = l2 >= 0.f ? l2 : NEG_SLOPE * l2;
        l3 = l3 >= 0.f ? l3 : NEG_SLOPE * l3;
        const float p0 = __expf(l0), p1 = __expf(l1);
        const float p2 = __expf(l2), p3 = __expf(l3);
        den += p0 + p1 + p2 + p3;
        a0 += p0 * bf2f(x0.x) + p1 * bf2f(x1.x) + p2 * bf2f(x2.x) + p3 * bf2f(x3.x);
        a1 += p0 * bf2f(x0.y) + p1 * bf2f(x1.y) + p2 * bf2f(x2.y) + p3 * bf2f(x3.y);
        a2 += p0 * bf2f(x0.z) + p1 * bf2f(x1.z) + p2 * bf2f(x2.z) + p3 * bf2f(x3.z);
        a3 += p0 * bf2f(x0.w) + p1 * bf2f(x1.w) + p2 * bf2f(x2.w) + p3 * bf2f(x3.w);
    }
    for (; e < e1; ++e) {
        const int src = csr_src[e];
        float ee = s[src * 4 + h] + dn;
        ee = ee >= 0.f ? ee : NEG_SLOPE * ee;
        const float pe = __expf(ee);
        const ushort4 xs = *(const ushort4*)(xb + (size_t)src * 256 + lane * 4);
        a0 += pe * bf2f(xs.x); a1 += pe * bf2f(xs.y);
        a2 += pe * bf2f(xs.z); a3 += pe * bf2f(xs.w);
        den += pe;
    }
    const float inv = 1.0f / den;
    ushort4 o;
    o.x = f2bf(a0 * inv); o.y = f2bf(a1 * inv);
    o.z = f2bf(a2 * inv); o.w = f2bf(a3 * inv);
    *(ushort4*)(hagg + (size_t)n * 256 + lane * 4) = o;
}

// ---------------------------------------------------------------------------
// BatchNorm stats over bf16 h (bias cancels in (h - mean), so ignored)
// ---------------------------------------------------------------------------
__global__ __launch_bounds__(256) void bn_stats_kernel(const ushort* __restrict__ hagg,
                                                       float* __restrict__ gsum,
                                                       float* __restrict__ gsumsq)
{
    const int c = threadIdx.x;
    float sum = 0.f, sq = 0.f;
    for (int r = blockIdx.x; r < N_NODES; r += gridDim.x) {
        const float v = bf2f(hagg[(size_t)r * 256 + c]);
        sum += v;
        sq += v * v;
    }
    atomicAdd(&gsum[c], sum);
    atomicAdd(&gsumsq[c], sq);
}

__global__ __launch_bounds__(256) void bn_final_kernel(const float* __restrict__ gsum,
                                                       const float* __restrict__ gsumsq,
                                                       const float* __restrict__ gamma,
                                                       float* __restrict__ meanArr,
                                                       float* __restrict__ scaleArr)
{
    const int c = threadIdx.x;
    const float m = gsum[c] * (1.0f / N_NODES);
    const float var = gsumsq[c] * (1.0f / N_NODES) - m * m;
    meanArr[c] = m;
    scaleArr[c] = gamma[c] * rsqrtf(var + BN_EPS);
}

// ---------------------------------------------------------------------------
// Finalize: normalize + ELU + residual -> d_out (fp32)
// ---------------------------------------------------------------------------
__global__ __launch_bounds__(256) void finalize_kernel(const float* __restrict__ feature,
                                                       const ushort* __restrict__ hagg,
                                                       const float* __restrict__ meanArr,
                                                       const float* __restrict__ scaleArr,
                                                       const float* __restrict__ beta,
                                                       float* __restrict__ out)
{
    const size_t i = (size_t)blockIdx.x * 256 + threadIdx.x;  // float4 index
    const int c4 = (int)(i & 63);
    const ushort4 hv = ((const ushort4*)hagg)[i];
    const float4 m = ((const float4*)meanArr)[c4];
    const float4 sc = ((const float4*)scaleArr)[c4];
    const float4 b = ((const float4*)beta)[c4];
    const float4 f = ((const float4*)feature)[i];
    float r0 = (bf2f(hv.x) - m.x) * sc.x + b.x;
    float r1 = (bf2f(hv.y) - m.y) * sc.y + b.y;
    float r2 = (bf2f(hv.z) - m.z) * sc.z + b.z;
    float r3 = (bf2f(hv.w) - m.w) * sc.w + b.w;
    r0 = r0 > 0.f ? r0 : expm1f(r0);
    r1 = r1 > 0.f ? r1 : expm1f(r1);
    r2 = r2 > 0.f ? r2 : expm1f(r2);
    r3 = r3 > 0.f ? r3 : expm1f(r3);
    ((float4*)out)[i] = make_float4(r0 + f.x, r1 + f.y, r2 + f.z, r3 + f.w);
}

// ---------------------------------------------------------------------------
extern "C" void kernel_launch(void* const* d_in, const int* in_sizes, int n_in,
                              void* d_out, int out_size, void* d_ws, size_t ws_size,
                              hipStream_t stream)
{
    const float* feature = (const float*)d_in[0];
    const int*   ei      = (const int*)d_in[1];
    const float* W       = (const float*)d_in[2];
    const float* att_src = (const float*)d_in[3];
    const float* att_dst = (const float*)d_in[4];
    // d_in[5] = bias: cancels inside batchnorm, unused
    const float* gamma   = (const float*)d_in[6];
    const float* beta    = (const float*)d_in[7];
    float* out = (float*)d_out;

    char* w = (char*)d_ws;
    auto carve = [&](size_t bytes) {
        char* p = w;
        w += (bytes + 255) & ~(size_t)255;
        return p;
    };
    ushort* featb    = (ushort*)carve((size_t)N_NODES * 256 * 2);
    ushort* Wtb      = (ushort*)carve((size_t)256 * 256 * 2);
    ushort* xb       = (ushort*)carve((size_t)N_NODES * 256 * 2);
    ushort* hagg     = (ushort*)carve((size_t)N_NODES * 256 * 2);
    float*  s        = (float*)carve((size_t)N_NODES * 4 * 4);
    float*  dv       = (float*)carve((size_t)N_NODES * 4 * 4);
    int*    deg      = (int*)carve((size_t)N_NODES * 4);
    int*    offsets  = (int*)carve((size_t)(N_NODES + 1) * 4);
    int*    cursor   = (int*)carve((size_t)N_NODES * 4);
    int*    csr_src  = (int*)carve((size_t)N_EDGES * 4);
    int*    blocksum = (int*)carve((size_t)SCAN_BLOCKS * 4);
    int*    blockbase= (int*)carve((size_t)SCAN_BLOCKS * 4);
    float*  gsum     = (float*)carve(256 * 4);
    float*  gsumsq   = (float*)carve(256 * 4);
    float*  meanArr  = (float*)carve(256 * 4);
    float*  scaleArr = (float*)carve(256 * 4);

    hipMemsetAsync(deg, 0, (size_t)N_NODES * 4, stream);

    convert_hist_kernel<<<FEAT_CONV_BLOCKS + 256 + HIST_BLOCKS, 256, 0, stream>>>(
        feature, W, ei, featb, Wtb, deg);
    scan1_kernel<<<SCAN_BLOCKS, 256, 0, stream>>>(deg, offsets, blocksum);
    scan2_kernel<<<1, 256, 0, stream>>>(blocksum, blockbase, gsum, gsumsq);
    scan3_kernel<<<SCAN_BLOCKS, 256, 0, stream>>>(blockbase, offsets, cursor);
    scatter_kernel<<<3125, 256, 0, stream>>>(ei, cursor, csr_src);
    gemm_kernel<<<dim3(2, 391), 256, 0, stream>>>(featb, Wtb, att_src, att_dst, xb, s, dv);
    aggregate_kernel<<<12500, 256, 0, stream>>>(xb, s, dv, offsets, csr_src, hagg);
    bn_stats_kernel<<<256, 256, 0, stream>>>(hagg, gsum, gsumsq);
    bn_final_kernel<<<1, 256, 0, stream>>>(gsum, gsumsq, gamma, meanArr, scaleArr);
    finalize_kernel<<<12500, 256, 0, stream>>>(feature, hagg, meanArr, scaleArr, beta, out);
}

// Round 4
// 353.055 us; speedup vs baseline: 1.7630x; 1.0402x over previous
//
#include <hip/hip_runtime.h>

#define N_NODES 50000
#define N_EDGES 800000
#define NEG_SLOPE 0.2f
#define BN_EPS  1e-5f

typedef short bf16x8 __attribute__((ext_vector_type(8)));
typedef float floatx4 __attribute__((ext_vector_type(4)));

__device__ inline ushort f2bf(float f) {
    union { float f; unsigned u; } v; v.f = f;
    unsigned r = v.u + 0x7fff + ((v.u >> 16) & 1);
    return (ushort)(r >> 16);
}
__device__ inline float bf2f(ushort h) {
    union { unsigned u; float f; } v; v.u = ((unsigned)h) << 16;
    return v.f;
}

// ---------------------------------------------------------------------------
// Prep: W fp32 [K][N] -> Wt bf16 [N][K]  (blocks 0..255)
//       histogram of dst into deg        (blocks 256..3380)
// deg zeroed by hipMemsetAsync before this kernel.
// ---------------------------------------------------------------------------
#define HIST_BLOCKS 3125
__global__ __launch_bounds__(256) void prep_kernel(const float* __restrict__ W,
                                                   const int* __restrict__ ei,
                                                   ushort* __restrict__ Wtb,
                                                   int* __restrict__ deg)
{
    const int b = blockIdx.x;
    if (b < 256) {
        const int n = b;                 // output col
        const int k = threadIdx.x;
        Wtb[n * 256 + k] = f2bf(W[k * 256 + n]);
    } else {
        const int e = (b - 256) * 256 + threadIdx.x;
        if (e < N_EDGES) atomicAdd(&deg[ei[N_EDGES + e]], 1);
    }
}

// ---------------------------------------------------------------------------
// Multi-block exclusive scan of deg[50000] -> offsets, cursor
// ---------------------------------------------------------------------------
#define SCAN_BLOCKS 196  // 196*256 = 50176 >= 50000
__global__ __launch_bounds__(256) void scan1_kernel(const int* __restrict__ deg,
                                                    int* __restrict__ offsets,
                                                    int* __restrict__ blocksum)
{
    __shared__ int sm[256];
    const int t = threadIdx.x;
    const int i = blockIdx.x * 256 + t;
    const int v = (i < N_NODES) ? deg[i] : 0;
    sm[t] = v;
    __syncthreads();
#pragma unroll
    for (int off = 1; off < 256; off <<= 1) {
        const int u = (t >= off) ? sm[t - off] : 0;
        __syncthreads();
        sm[t] += u;
        __syncthreads();
    }
    if (i < N_NODES) offsets[i] = sm[t] - v;  // block-local exclusive
    if (t == 255) blocksum[blockIdx.x] = sm[255];
}

__global__ __launch_bounds__(256) void scan2_kernel(const int* __restrict__ blocksum,
                                                    int* __restrict__ blockbase,
                                                    float* __restrict__ gsum,
                                                    float* __restrict__ gsumsq)
{
    __shared__ int sm[256];
    const int t = threadIdx.x;
    const int v = (t < SCAN_BLOCKS) ? blocksum[t] : 0;
    sm[t] = v;
    __syncthreads();
#pragma unroll
    for (int off = 1; off < 256; off <<= 1) {
        const int u = (t >= off) ? sm[t - off] : 0;
        __syncthreads();
        sm[t] += u;
        __syncthreads();
    }
    if (t < SCAN_BLOCKS) blockbase[t] = sm[t] - v;
    // piggyback: zero BN accumulators (runs before bn_stats)
    gsum[t] = 0.f;
    gsumsq[t] = 0.f;
}

__global__ __launch_bounds__(256) void scan3_kernel(const int* __restrict__ blockbase,
                                                    int* __restrict__ offsets,
                                                    int* __restrict__ cursor)
{
    const int i = blockIdx.x * 256 + threadIdx.x;
    if (i < N_NODES) {
        const int o = offsets[i] + blockbase[blockIdx.x];
        offsets[i] = o;
        cursor[i] = o;
    }
    if (i == 0) offsets[N_NODES] = N_EDGES;
}

__global__ __launch_bounds__(256) void scatter_kernel(const int* __restrict__ ei,
                                                      int* __restrict__ cursor,
                                                      int* __restrict__ csr_src)
{
    const int e = blockIdx.x * 256 + threadIdx.x;
    if (e < N_EDGES) {
        const int src = ei[e];
        const int dst = ei[N_EDGES + e];
        const int pos = atomicAdd(&cursor[dst], 1);
        csr_src[pos] = src;
    }
}

// ---------------------------------------------------------------------------
// MFMA GEMM (fused fp32->bf16 convert of A in staging):
// xb[M,256] = bf16( feature @ W ), 128x128 tile, 4 waves of 64x64.
// Epilogue: per-node attention logits s,d (16-lane shuffle reduce) and
// PERMUTED xb stores: within each 64-col head block, position = l16*4 + ni
// (true col = ni*16 + l16) -> coalesced ushort4 stores.
// ---------------------------------------------------------------------------
#define LDSTRIDE 40  // 32 + 8 pad: 2-way max bank aliasing (free)
__global__ __launch_bounds__(256) void gemm_kernel(const float* __restrict__ A,
                                                   const ushort* __restrict__ Bt,
                                                   const float* __restrict__ att_src,
                                                   const float* __restrict__ att_dst,
                                                   ushort* __restrict__ Xb,
                                                   float* __restrict__ s,
                                                   float* __restrict__ d)
{
    __shared__ ushort As[128 * LDSTRIDE];
    __shared__ ushort Bs[128 * LDSTRIDE];
    const int tid = threadIdx.x;
    const int lane = tid & 63;
    const int wid = tid >> 6;
    const int wm = wid & 1, wn = wid >> 1;
    const int row0 = blockIdx.y * 128;
    const int col0 = blockIdx.x * 128;

    floatx4 acc[4][4] = {};  // [mi][ni]

    const int lr = tid >> 2;        // 0..63 (row base)
    const int lk = (tid & 3) * 8;   // 0,8,16,24 (k elem offset)

    for (int k0 = 0; k0 < 256; k0 += 32) {
#pragma unroll
        for (int r = 0; r < 2; ++r) {
            const int row = lr + r * 64;
            const int grow = row0 + row;
            union { ushort u[8]; ulonglong2 v; } cv;
            if (grow < N_NODES) {
                const float4 f0 = *(const float4*)(A + (size_t)grow * 256 + k0 + lk);
                const float4 f1 = *(const float4*)(A + (size_t)grow * 256 + k0 + lk + 4);
                cv.u[0] = f2bf(f0.x); cv.u[1] = f2bf(f0.y);
                cv.u[2] = f2bf(f0.z); cv.u[3] = f2bf(f0.w);
                cv.u[4] = f2bf(f1.x); cv.u[5] = f2bf(f1.y);
                cv.u[6] = f2bf(f1.z); cv.u[7] = f2bf(f1.w);
            } else {
                cv.v = ulonglong2{0ull, 0ull};
            }
            *(ulonglong2*)(As + row * LDSTRIDE + lk) = cv.v;
            const ulonglong2 bv = *(const ulonglong2*)(Bt + (size_t)(col0 + row) * 256 + k0 + lk);
            *(ulonglong2*)(Bs + row * LDSTRIDE + lk) = bv;
        }
        __syncthreads();
        const int quad = lane >> 4;
        const int l16 = lane & 15;
        bf16x8 afrag[4], bfrag[4];
#pragma unroll
        for (int mi = 0; mi < 4; ++mi)
            afrag[mi] = *(const bf16x8*)(As + (wm * 64 + mi * 16 + l16) * LDSTRIDE + quad * 8);
#pragma unroll
        for (int ni = 0; ni < 4; ++ni)
            bfrag[ni] = *(const bf16x8*)(Bs + (wn * 64 + ni * 16 + l16) * LDSTRIDE + quad * 8);
#pragma unroll
        for (int mi = 0; mi < 4; ++mi)
#pragma unroll
            for (int ni = 0; ni < 4; ++ni)
                acc[mi][ni] = __builtin_amdgcn_mfma_f32_16x16x32_bf16(afrag[mi], bfrag[ni], acc[mi][ni], 0, 0, 0);
        __syncthreads();
    }

    const int quad = lane >> 4;
    const int l16 = lane & 15;
    const int head = (col0 + wn * 64) >> 6;  // wave's 64 cols = one head
    float as_l[4], ad_l[4];
#pragma unroll
    for (int ni = 0; ni < 4; ++ni) {
        const int ch = head * 64 + ni * 16 + l16;  // true channel
        as_l[ni] = att_src[ch];
        ad_l[ni] = att_dst[ch];
    }
#pragma unroll
    for (int mi = 0; mi < 4; ++mi) {
#pragma unroll
        for (int r = 0; r < 4; ++r) {
            const int grow = row0 + wm * 64 + mi * 16 + quad * 4 + r;
            const bool ok = grow < N_NODES;
            float vs = 0.f, vd = 0.f;
            ushort4 o;
#pragma unroll
            for (int ni = 0; ni < 4; ++ni) {
                const float v = acc[mi][ni][r];
                vs += v * as_l[ni];
                vd += v * ad_l[ni];
                ((ushort*)&o)[ni] = f2bf(v);
            }
            if (ok)  // permuted: pos within head block = l16*4 + ni
                *(ushort4*)(Xb + (size_t)grow * 256 + head * 64 + l16 * 4) = o;
#pragma unroll
            for (int m = 8; m >= 1; m >>= 1) {
                vs += __shfl_xor(vs, m);
                vd += __shfl_xor(vd, m);
            }
            if (l16 == 0 && ok) {
                s[grow * 4 + head] = vs;
                d[grow * 4 + head] = vd;
            }
        }
    }
}

// ---------------------------------------------------------------------------
// Aggregate: softmax-weighted gather per dst node (self-loop included).
// One wave per node; lane l owns permuted positions [4l,4l+4); head = l>>4
// (permutation is head-block-local, so head mapping is preserved).
// Edge loop unrolled x8 for gather ILP. Output h bf16, permuted layout.
// ---------------------------------------------------------------------------
__global__ __launch_bounds__(256) void aggregate_kernel(const ushort* __restrict__ xb,
                                                        const float* __restrict__ s,
                                                        const float* __restrict__ d,
                                                        const int* __restrict__ offsets,
                                                        const int* __restrict__ csr_src,
                                                        ushort* __restrict__ hagg)
{
    const int wid = threadIdx.x >> 6;
    const int lane = threadIdx.x & 63;
    const int n = blockIdx.x * 4 + wid;
    if (n >= N_NODES) return;
    const int h = lane >> 4;
    const float dn = d[n * 4 + h];
    const float sn = s[n * 4 + h];
    const ushort4 xr = *(const ushort4*)(xb + (size_t)n * 256 + lane * 4);
    float eself = sn + dn;
    eself = eself >= 0.f ? eself : NEG_SLOPE * eself;
    const float pself = __expf(eself);
    float den = pself;
    float a0 = pself * bf2f(xr.x), a1 = pself * bf2f(xr.y);
    float a2 = pself * bf2f(xr.z), a3 = pself * bf2f(xr.w);
    const int e0 = offsets[n];
    const int e1 = offsets[n + 1];
    int e = e0;
    for (; e + 8 <= e1; e += 8) {
        int si[8];
        float lg[8];
        ushort4 xv[8];
#pragma unroll
        for (int j = 0; j < 8; ++j) si[j] = csr_src[e + j];
#pragma unroll
        for (int j = 0; j < 8; ++j) lg[j] = s[si[j] * 4 + h] + dn;
#pragma unroll
        for (int j = 0; j < 8; ++j)
            xv[j] = *(const ushort4*)(xb + (size_t)si[j] * 256 + lane * 4);
#pragma unroll
        for (int j = 0; j < 8; ++j) {
            float l = lg[j];
            l = l >= 0.f ? l : NEG_SLOPE * l;
            const float p = __expf(l);
            den += p;
            a0 += p * bf2f(xv[j].x);
            a1 += p * bf2f(xv[j].y);
            a2 += p * bf2f(xv[j].z);
            a3 += p * bf2f(xv[j].w);
        }
    }
    for (; e < e1; ++e) {
        const int src = csr_src[e];
        float ee = s[src * 4 + h] + dn;
        ee = ee >= 0.f ? ee : NEG_SLOPE * ee;
        const float pe = __expf(ee);
        const ushort4 xs = *(const ushort4*)(xb + (size_t)src * 256 + lane * 4);
        a0 += pe * bf2f(xs.x); a1 += pe * bf2f(xs.y);
        a2 += pe * bf2f(xs.z); a3 += pe * bf2f(xs.w);
        den += pe;
    }
    const float inv = 1.0f / den;
    ushort4 o;
    o.x = f2bf(a0 * inv); o.y = f2bf(a1 * inv);
    o.z = f2bf(a2 * inv); o.w = f2bf(a3 * inv);
    *(ushort4*)(hagg + (size_t)n * 256 + lane * 4) = o;
}

// ---------------------------------------------------------------------------
// BatchNorm stats over bf16 h (permuted channels; bias cancels, ignored).
// 784 blocks x 64 rows, local accumulate, one atomic pair per thread.
// ---------------------------------------------------------------------------
#define BN_BLOCKS 784  // 784*64 = 50176 >= 50000
__global__ __launch_bounds__(256) void bn_stats_kernel(const ushort* __restrict__ hagg,
                                                       float* __restrict__ gsum,
                                                       float* __restrict__ gsumsq)
{
    const int c = threadIdx.x;  // permuted channel
    const int r0 = blockIdx.x * 64;
    float sum = 0.f, sq = 0.f;
#pragma unroll 4
    for (int i = 0; i < 64; ++i) {
        const int r = r0 + i;
        if (r < N_NODES) {
            const float v = bf2f(hagg[(size_t)r * 256 + c]);
            sum += v;
            sq += v * v;
        }
    }
    atomicAdd(&gsum[c], sum);
    atomicAdd(&gsumsq[c], sq);
}

// ---------------------------------------------------------------------------
// Finalize (fused bn_final): per-lane computes mean/scale for its 4 permuted
// channels from gsum/gsumsq (L2-resident), then normalize+ELU+residual.
// Reads hagg permuted (ushort4 coalesced); writes d_out in TRUE layout via
// 4 per-lane scalar stores (each instruction = 4 x 64B segments, coalesced).
// One wave per 4 rows.
// ---------------------------------------------------------------------------
__global__ __launch_bounds__(256) void finalize_kernel(const float* __restrict__ feature,
                                                       const ushort* __restrict__ hagg,
                                                       const float* __restrict__ gsum,
                                                       const float* __restrict__ gsumsq,
                                                       const float* __restrict__ gamma,
                                                       const float* __restrict__ beta,
                                                       float* __restrict__ out)
{
    const int wid = threadIdx.x >> 6;
    const int lane = threadIdx.x & 63;
    const int wgid = blockIdx.x * 4 + wid;   // 0..12499
    const int hblk = lane >> 4;
    const int l16 = lane & 15;

    float meanv[4], scalev[4], betav[4];
    int tc[4];
#pragma unroll
    for (int j = 0; j < 4; ++j) {
        const int p = lane * 4 + j;                 // permuted channel
        tc[j] = hblk * 64 + j * 16 + l16;           // true channel
        const float m = gsum[p] * (1.0f / N_NODES);
        const float var = gsumsq[p] * (1.0f / N_NODES) - m * m;
        meanv[j] = m;
        scalev[j] = gamma[tc[j]] * rsqrtf(var + BN_EPS);
        betav[j] = beta[tc[j]];
    }
#pragma unroll
    for (int rr = 0; rr < 4; ++rr) {
        const int n = wgid * 4 + rr;
        const ushort4 hv = *(const ushort4*)(hagg + (size_t)n * 256 + lane * 4);
        const float hvf[4] = {bf2f(hv.x), bf2f(hv.y), bf2f(hv.z), bf2f(hv.w)};
#pragma unroll
        for (int j = 0; j < 4; ++j) {
            float r = (hvf[j] - meanv[j]) * scalev[j] + betav[j];
            r = r > 0.f ? r : expm1f(r);
            out[(size_t)n * 256 + tc[j]] = r + feature[(size_t)n * 256 + tc[j]];
        }
    }
}

// ---------------------------------------------------------------------------
extern "C" void kernel_launch(void* const* d_in, const int* in_sizes, int n_in,
                              void* d_out, int out_size, void* d_ws, size_t ws_size,
                              hipStream_t stream)
{
    const float* feature = (const float*)d_in[0];
    const int*   ei      = (const int*)d_in[1];
    const float* W       = (const float*)d_in[2];
    const float* att_src = (const float*)d_in[3];
    const float* att_dst = (const float*)d_in[4];
    // d_in[5] = bias: cancels inside batchnorm, unused
    const float* gamma   = (const float*)d_in[6];
    const float* beta    = (const float*)d_in[7];
    float* out = (float*)d_out;

    char* w = (char*)d_ws;
    auto carve = [&](size_t bytes) {
        char* p = w;
        w += (bytes + 255) & ~(size_t)255;
        return p;
    };
    ushort* Wtb      = (ushort*)carve((size_t)256 * 256 * 2);
    ushort* xb       = (ushort*)carve((size_t)N_NODES * 256 * 2);
    ushort* hagg     = (ushort*)carve((size_t)N_NODES * 256 * 2);
    float*  s        = (float*)carve((size_t)N_NODES * 4 * 4);
    float*  dv       = (float*)carve((size_t)N_NODES * 4 * 4);
    int*    deg      = (int*)carve((size_t)N_NODES * 4);
    int*    offsets  = (int*)carve((size_t)(N_NODES + 1) * 4);
    int*    cursor   = (int*)carve((size_t)N_NODES * 4);
    int*    csr_src  = (int*)carve((size_t)N_EDGES * 4);
    int*    blocksum = (int*)carve((size_t)SCAN_BLOCKS * 4);
    int*    blockbase= (int*)carve((size_t)SCAN_BLOCKS * 4);
    float*  gsum     = (float*)carve(256 * 4);
    float*  gsumsq   = (float*)carve(256 * 4);

    hipMemsetAsync(deg, 0, (size_t)N_NODES * 4, stream);

    prep_kernel<<<256 + HIST_BLOCKS, 256, 0, stream>>>(W, ei, Wtb, deg);
    scan1_kernel<<<SCAN_BLOCKS, 256, 0, stream>>>(deg, offsets, blocksum);
    scan2_kernel<<<1, 256, 0, stream>>>(blocksum, blockbase, gsum, gsumsq);
    scan3_kernel<<<SCAN_BLOCKS, 256, 0, stream>>>(blockbase, offsets, cursor);
    scatter_kernel<<<3125, 256, 0, stream>>>(ei, cursor, csr_src);
    gemm_kernel<<<dim3(2, 391), 256, 0, stream>>>(feature, Wtb, att_src, att_dst, xb, s, dv);
    aggregate_kernel<<<12500, 256, 0, stream>>>(xb, s, dv, offsets, csr_src, hagg);
    bn_stats_kernel<<<BN_BLOCKS, 256, 0, stream>>>(hagg, gsum, gsumsq);
    finalize_kernel<<<3125, 256, 0, stream>>>(feature, hagg, gsum, gsumsq, gamma, beta, out);
}

// Round 5
// 294.430 us; speedup vs baseline: 2.1140x; 1.1991x over previous
//
#include <hip/hip_runtime.h>

#define N_NODES 50000
#define N_EDGES 800000
#define NEG_SLOPE 0.2f
#define BN_EPS  1e-5f

#define NBLK 256            // edge chunks for counting sort
#define EDGES_PER_BLK 3125  // 256*3125 = 800000 exactly
#define NBUCKET 196         // ceil(50000/256); padded to 256 in counts

typedef short bf16x8 __attribute__((ext_vector_type(8)));
typedef float floatx4 __attribute__((ext_vector_type(4)));

__device__ inline ushort f2bf(float f) {
    union { float f; unsigned u; } v; v.f = f;
    unsigned r = v.u + 0x7fff + ((v.u >> 16) & 1);
    return (ushort)(r >> 16);
}
__device__ inline float bf2f(ushort h) {
    union { unsigned u; float f; } v; v.u = ((unsigned)h) << 16;
    return v.f;
}

// ---------------------------------------------------------------------------
// Pass A + W-transpose fused:
//   blocks [0,256)   : LDS histogram of coarse bucket (dst>>8) over this
//                      block's 3125-edge chunk -> counts[bucket*256+blk]
//   blocks [256,512) : W fp32 [K][N] -> Wt bf16 [N][K]
// NO global atomics.
// ---------------------------------------------------------------------------
__global__ __launch_bounds__(256) void count_wt_kernel(const int* __restrict__ ei,
                                                       const float* __restrict__ W,
                                                       int* __restrict__ counts,
                                                       ushort* __restrict__ Wtb)
{
    __shared__ int hist[256];
    const int t = threadIdx.x;
    const int b = blockIdx.x;
    if (b < NBLK) {
        hist[t] = 0;
        __syncthreads();
        const int e0 = b * EDGES_PER_BLK;
        for (int e = e0 + t; e < e0 + EDGES_PER_BLK; e += 256)
            atomicAdd(&hist[ei[N_EDGES + e] >> 8], 1);
        __syncthreads();
        counts[t * NBLK + b] = hist[t];   // bucket-major layout for the scan
    } else {
        const int n = b - NBLK;           // output col
        Wtb[n * 256 + t] = f2bf(W[t * 256 + n]);
    }
}

// ---------------------------------------------------------------------------
// Exclusive scan of counts[65536] (bucket-major => linear order is correct):
// sscan1 (256 blocks) -> local excl + blocksum; sscan2 (1 block) -> blockbase
// (+ zero BN accumulators); sscan3 (256 blocks) -> add base in place.
// ---------------------------------------------------------------------------
__global__ __launch_bounds__(256) void sscan1_kernel(int* __restrict__ counts,
                                                     int* __restrict__ blocksum)
{
    __shared__ int sm[256];
    const int t = threadIdx.x;
    const int i = blockIdx.x * 256 + t;
    const int v = counts[i];
    sm[t] = v;
    __syncthreads();
#pragma unroll
    for (int off = 1; off < 256; off <<= 1) {
        const int u = (t >= off) ? sm[t - off] : 0;
        __syncthreads();
        sm[t] += u;
        __syncthreads();
    }
    counts[i] = sm[t] - v;  // block-local exclusive
    if (t == 255) blocksum[blockIdx.x] = sm[255];
}

__global__ __launch_bounds__(256) void sscan2_kernel(const int* __restrict__ blocksum,
                                                     int* __restrict__ blockbase,
                                                     float* __restrict__ gsum,
                                                     float* __restrict__ gsumsq)
{
    __shared__ int sm[256];
    const int t = threadIdx.x;
    const int v = blocksum[t];
    sm[t] = v;
    __syncthreads();
#pragma unroll
    for (int off = 1; off < 256; off <<= 1) {
        const int u = (t >= off) ? sm[t - off] : 0;
        __syncthreads();
        sm[t] += u;
        __syncthreads();
    }
    blockbase[t] = sm[t] - v;
    // piggyback: zero BN accumulators (runs before bn_stats)
    gsum[t] = 0.f;
    gsumsq[t] = 0.f;
}

__global__ __launch_bounds__(256) void sscan3_kernel(int* __restrict__ counts,
                                                     const int* __restrict__ blockbase)
{
    const int i = blockIdx.x * 256 + threadIdx.x;
    counts[i] += blockbase[blockIdx.x];
}

// ---------------------------------------------------------------------------
// Pass B: bucket-partitioned scatter. Block blk re-reads its edge chunk;
// LDS cursors seeded from scanned counts[bucket*256+blk]; writes (dst,src)
// pairs. LDS atomics only.
// ---------------------------------------------------------------------------
__global__ __launch_bounds__(256) void bucket_scatter_kernel(const int* __restrict__ ei,
                                                             const int* __restrict__ counts,
                                                             int2* __restrict__ tmp)
{
    __shared__ int cursor[256];
    const int t = threadIdx.x;
    const int blk = blockIdx.x;
    cursor[t] = counts[t * NBLK + blk];
    __syncthreads();
    const int e0 = blk * EDGES_PER_BLK;
    for (int e = e0 + t; e < e0 + EDGES_PER_BLK; e += 256) {
        const int src = ei[e];
        const int dst = ei[N_EDGES + e];
        const int pos = atomicAdd(&cursor[dst >> 8], 1);
        tmp[pos] = make_int2(dst, src);
    }
}

// ---------------------------------------------------------------------------
// Pass C: per-bucket CSR build. One block per bucket (~4080 edges):
// LDS 256-bin hist over dst&255 -> LDS scan -> offsets[]; then LDS-cursor
// scatter of src into csr_src. LDS atomics only. Two streaming passes over
// the bucket's edges (L2-hot second time).
// ---------------------------------------------------------------------------
__global__ __launch_bounds__(256) void bucket_build_kernel(const int2* __restrict__ tmp,
                                                           const int* __restrict__ counts,
                                                           int* __restrict__ offsets,
                                                           int* __restrict__ csr_src)
{
    __shared__ int hist[256];
    __shared__ int scanbuf[256];
    __shared__ int cursor[256];
    const int t = threadIdx.x;
    const int b = blockIdx.x;                 // bucket, nodes [b*256, b*256+256)
    const int start = counts[b * NBLK];       // global base of bucket b
    const int end   = counts[(b + 1) * NBLK]; // buckets >=196 are empty => ==E for b=195
    hist[t] = 0;
    __syncthreads();
    for (int e = start + t; e < end; e += 256)
        atomicAdd(&hist[tmp[e].x & 255], 1);
    __syncthreads();
    const int v = hist[t];
    scanbuf[t] = v;
    __syncthreads();
#pragma unroll
    for (int off = 1; off < 256; off <<= 1) {
        const int u = (t >= off) ? scanbuf[t - off] : 0;
        __syncthreads();
        scanbuf[t] += u;
        __syncthreads();
    }
    const int excl = start + scanbuf[t] - v;
    cursor[t] = excl;
    const int node = b * 256 + t;
    if (node < N_NODES) offsets[node] = excl;
    if (b == 0 && t == 0) offsets[N_NODES] = N_EDGES;
    __syncthreads();
    for (int e = start + t; e < end; e += 256) {
        const int2 p = tmp[e];
        const int pos = atomicAdd(&cursor[p.x & 255], 1);
        csr_src[pos] = p.y;
    }
}

// ---------------------------------------------------------------------------
// MFMA GEMM (fused fp32->bf16 convert of A in staging):
// xb[M,256] = bf16( feature @ W ), 128x128 tile, 4 waves of 64x64.
// Epilogue: per-node attention logits s,d (16-lane shuffle reduce) and
// PERMUTED xb stores: within each 64-col head block, position = l16*4 + ni
// (true col = ni*16 + l16) -> coalesced ushort4 stores.
// ---------------------------------------------------------------------------
#define LDSTRIDE 40  // 32 + 8 pad: 2-way max bank aliasing (free)
__global__ __launch_bounds__(256) void gemm_kernel(const float* __restrict__ A,
                                                   const ushort* __restrict__ Bt,
                                                   const float* __restrict__ att_src,
                                                   const float* __restrict__ att_dst,
                                                   ushort* __restrict__ Xb,
                                                   float* __restrict__ s,
                                                   float* __restrict__ d)
{
    __shared__ ushort As[128 * LDSTRIDE];
    __shared__ ushort Bs[128 * LDSTRIDE];
    const int tid = threadIdx.x;
    const int lane = tid & 63;
    const int wid = tid >> 6;
    const int wm = wid & 1, wn = wid >> 1;
    const int row0 = blockIdx.y * 128;
    const int col0 = blockIdx.x * 128;

    floatx4 acc[4][4] = {};  // [mi][ni]

    const int lr = tid >> 2;        // 0..63 (row base)
    const int lk = (tid & 3) * 8;   // 0,8,16,24 (k elem offset)

    for (int k0 = 0; k0 < 256; k0 += 32) {
#pragma unroll
        for (int r = 0; r < 2; ++r) {
            const int row = lr + r * 64;
            const int grow = row0 + row;
            union { ushort u[8]; ulonglong2 v; } cv;
            if (grow < N_NODES) {
                const float4 f0 = *(const float4*)(A + (size_t)grow * 256 + k0 + lk);
                const float4 f1 = *(const float4*)(A + (size_t)grow * 256 + k0 + lk + 4);
                cv.u[0] = f2bf(f0.x); cv.u[1] = f2bf(f0.y);
                cv.u[2] = f2bf(f0.z); cv.u[3] = f2bf(f0.w);
                cv.u[4] = f2bf(f1.x); cv.u[5] = f2bf(f1.y);
                cv.u[6] = f2bf(f1.z); cv.u[7] = f2bf(f1.w);
            } else {
                cv.v = ulonglong2{0ull, 0ull};
            }
            *(ulonglong2*)(As + row * LDSTRIDE + lk) = cv.v;
            const ulonglong2 bv = *(const ulonglong2*)(Bt + (size_t)(col0 + row) * 256 + k0 + lk);
            *(ulonglong2*)(Bs + row * LDSTRIDE + lk) = bv;
        }
        __syncthreads();
        const int quad = lane >> 4;
        const int l16 = lane & 15;
        bf16x8 afrag[4], bfrag[4];
#pragma unroll
        for (int mi = 0; mi < 4; ++mi)
            afrag[mi] = *(const bf16x8*)(As + (wm * 64 + mi * 16 + l16) * LDSTRIDE + quad * 8);
#pragma unroll
        for (int ni = 0; ni < 4; ++ni)
            bfrag[ni] = *(const bf16x8*)(Bs + (wn * 64 + ni * 16 + l16) * LDSTRIDE + quad * 8);
#pragma unroll
        for (int mi = 0; mi < 4; ++mi)
#pragma unroll
            for (int ni = 0; ni < 4; ++ni)
                acc[mi][ni] = __builtin_amdgcn_mfma_f32_16x16x32_bf16(afrag[mi], bfrag[ni], acc[mi][ni], 0, 0, 0);
        __syncthreads();
    }

    const int quad = lane >> 4;
    const int l16 = lane & 15;
    const int head = (col0 + wn * 64) >> 6;  // wave's 64 cols = one head
    float as_l[4], ad_l[4];
#pragma unroll
    for (int ni = 0; ni < 4; ++ni) {
        const int ch = head * 64 + ni * 16 + l16;  // true channel
        as_l[ni] = att_src[ch];
        ad_l[ni] = att_dst[ch];
    }
#pragma unroll
    for (int mi = 0; mi < 4; ++mi) {
#pragma unroll
        for (int r = 0; r < 4; ++r) {
            const int grow = row0 + wm * 64 + mi * 16 + quad * 4 + r;
            const bool ok = grow < N_NODES;
            float vs = 0.f, vd = 0.f;
            ushort4 o;
#pragma unroll
            for (int ni = 0; ni < 4; ++ni) {
                const float v = acc[mi][ni][r];
                vs += v * as_l[ni];
                vd += v * ad_l[ni];
                ((ushort*)&o)[ni] = f2bf(v);
            }
            if (ok)  // permuted: pos within head block = l16*4 + ni
                *(ushort4*)(Xb + (size_t)grow * 256 + head * 64 + l16 * 4) = o;
#pragma unroll
            for (int m = 8; m >= 1; m >>= 1) {
                vs += __shfl_xor(vs, m);
                vd += __shfl_xor(vd, m);
            }
            if (l16 == 0 && ok) {
                s[grow * 4 + head] = vs;
                d[grow * 4 + head] = vd;
            }
        }
    }
}

// ---------------------------------------------------------------------------
// Aggregate: softmax-weighted gather per dst node (self-loop included).
// One wave per node; lane l owns permuted positions [4l,4l+4); head = l>>4.
// Edge loop unrolled x8 for gather ILP. Output h bf16, permuted layout.
// ---------------------------------------------------------------------------
__global__ __launch_bounds__(256) void aggregate_kernel(const ushort* __restrict__ xb,
                                                        const float* __restrict__ s,
                                                        const float* __restrict__ d,
                                                        const int* __restrict__ offsets,
                                                        const int* __restrict__ csr_src,
                                                        ushort* __restrict__ hagg)
{
    const int wid = threadIdx.x >> 6;
    const int lane = threadIdx.x & 63;
    const int n = blockIdx.x * 4 + wid;
    if (n >= N_NODES) return;
    const int h = lane >> 4;
    const float dn = d[n * 4 + h];
    const float sn = s[n * 4 + h];
    const ushort4 xr = *(const ushort4*)(xb + (size_t)n * 256 + lane * 4);
    float eself = sn + dn;
    eself = eself >= 0.f ? eself : NEG_SLOPE * eself;
    const float pself = __expf(eself);
    float den = pself;
    float a0 = pself * bf2f(xr.x), a1 = pself * bf2f(xr.y);
    float a2 = pself * bf2f(xr.z), a3 = pself * bf2f(xr.w);
    const int e0 = offsets[n];
    const int e1 = offsets[n + 1];
    int e = e0;
    for (; e + 8 <= e1; e += 8) {
        int si[8];
        float lg[8];
        ushort4 xv[8];
#pragma unroll
        for (int j = 0; j < 8; ++j) si[j] = csr_src[e + j];
#pragma unroll
        for (int j = 0; j < 8; ++j) lg[j] = s[si[j] * 4 + h] + dn;
#pragma unroll
        for (int j = 0; j < 8; ++j)
            xv[j] = *(const ushort4*)(xb + (size_t)si[j] * 256 + lane * 4);
#pragma unroll
        for (int j = 0; j < 8; ++j) {
            float l = lg[j];
            l = l >= 0.f ? l : NEG_SLOPE * l;
            const float p = __expf(l);
            den += p;
            a0 += p * bf2f(xv[j].x);
            a1 += p * bf2f(xv[j].y);
            a2 += p * bf2f(xv[j].z);
            a3 += p * bf2f(xv[j].w);
        }
    }
    for (; e < e1; ++e) {
        const int src = csr_src[e];
        float ee = s[src * 4 + h] + dn;
        ee = ee >= 0.f ? ee : NEG_SLOPE * ee;
        const float pe = __expf(ee);
        const ushort4 xs = *(const ushort4*)(xb + (size_t)src * 256 + lane * 4);
        a0 += pe * bf2f(xs.x); a1 += pe * bf2f(xs.y);
        a2 += pe * bf2f(xs.z); a3 += pe * bf2f(xs.w);
        den += pe;
    }
    const float inv = 1.0f / den;
    ushort4 o;
    o.x = f2bf(a0 * inv); o.y = f2bf(a1 * inv);
    o.z = f2bf(a2 * inv); o.w = f2bf(a3 * inv);
    *(ushort4*)(hagg + (size_t)n * 256 + lane * 4) = o;
}

// ---------------------------------------------------------------------------
// BatchNorm stats over bf16 h (permuted channels; bias cancels, ignored).
// 784 blocks x 64 rows, local accumulate, one atomic pair per thread.
// ---------------------------------------------------------------------------
#define BN_BLOCKS 784  // 784*64 = 50176 >= 50000
__global__ __launch_bounds__(256) void bn_stats_kernel(const ushort* __restrict__ hagg,
                                                       float* __restrict__ gsum,
                                                       float* __restrict__ gsumsq)
{
    const int c = threadIdx.x;  // permuted channel
    const int r0 = blockIdx.x * 64;
    float sum = 0.f, sq = 0.f;
#pragma unroll 4
    for (int i = 0; i < 64; ++i) {
        const int r = r0 + i;
        if (r < N_NODES) {
            const float v = bf2f(hagg[(size_t)r * 256 + c]);
            sum += v;
            sq += v * v;
        }
    }
    atomicAdd(&gsum[c], sum);
    atomicAdd(&gsumsq[c], sq);
}

// ---------------------------------------------------------------------------
// Finalize (fused bn_final): per-lane computes mean/scale for its 4 permuted
// channels from gsum/gsumsq (L2-resident), then normalize+ELU+residual.
// ---------------------------------------------------------------------------
__global__ __launch_bounds__(256) void finalize_kernel(const float* __restrict__ feature,
                                                       const ushort* __restrict__ hagg,
                                                       const float* __restrict__ gsum,
                                                       const float* __restrict__ gsumsq,
                                                       const float* __restrict__ gamma,
                                                       const float* __restrict__ beta,
                                                       float* __restrict__ out)
{
    const int wid = threadIdx.x >> 6;
    const int lane = threadIdx.x & 63;
    const int wgid = blockIdx.x * 4 + wid;   // 0..12499
    const int hblk = lane >> 4;
    const int l16 = lane & 15;

    float meanv[4], scalev[4], betav[4];
    int tc[4];
#pragma unroll
    for (int j = 0; j < 4; ++j) {
        const int p = lane * 4 + j;                 // permuted channel
        tc[j] = hblk * 64 + j * 16 + l16;           // true channel
        const float m = gsum[p] * (1.0f / N_NODES);
        const float var = gsumsq[p] * (1.0f / N_NODES) - m * m;
        meanv[j] = m;
        scalev[j] = gamma[tc[j]] * rsqrtf(var + BN_EPS);
        betav[j] = beta[tc[j]];
    }
#pragma unroll
    for (int rr = 0; rr < 4; ++rr) {
        const int n = wgid * 4 + rr;
        const ushort4 hv = *(const ushort4*)(hagg + (size_t)n * 256 + lane * 4);
        const float hvf[4] = {bf2f(hv.x), bf2f(hv.y), bf2f(hv.z), bf2f(hv.w)};
#pragma unroll
        for (int j = 0; j < 4; ++j) {
            float r = (hvf[j] - meanv[j]) * scalev[j] + betav[j];
            r = r > 0.f ? r : expm1f(r);
            out[(size_t)n * 256 + tc[j]] = r + feature[(size_t)n * 256 + tc[j]];
        }
    }
}

// ---------------------------------------------------------------------------
extern "C" void kernel_launch(void* const* d_in, const int* in_sizes, int n_in,
                              void* d_out, int out_size, void* d_ws, size_t ws_size,
                              hipStream_t stream)
{
    const float* feature = (const float*)d_in[0];
    const int*   ei      = (const int*)d_in[1];
    const float* W       = (const float*)d_in[2];
    const float* att_src = (const float*)d_in[3];
    const float* att_dst = (const float*)d_in[4];
    // d_in[5] = bias: cancels inside batchnorm, unused
    const float* gamma   = (const float*)d_in[6];
    const float* beta    = (const float*)d_in[7];
    float* out = (float*)d_out;

    char* w = (char*)d_ws;
    auto carve = [&](size_t bytes) {
        char* p = w;
        w += (bytes + 255) & ~(size_t)255;
        return p;
    };
    ushort* Wtb      = (ushort*)carve((size_t)256 * 256 * 2);
    ushort* xb       = (ushort*)carve((size_t)N_NODES * 256 * 2);
    ushort* hagg     = (ushort*)carve((size_t)N_NODES * 256 * 2);
    float*  s        = (float*)carve((size_t)N_NODES * 4 * 4);
    float*  dv       = (float*)carve((size_t)N_NODES * 4 * 4);
    int*    counts   = (int*)carve((size_t)256 * NBLK * 4);   // 65536 entries
    int*    offsets  = (int*)carve((size_t)(N_NODES + 1) * 4);
    int*    csr_src  = (int*)carve((size_t)N_EDGES * 4);
    int*    blocksum = (int*)carve((size_t)256 * 4);
    int*    blockbase= (int*)carve((size_t)256 * 4);
    float*  gsum     = (float*)carve(256 * 4);
    float*  gsumsq   = (float*)carve(256 * 4);
    // tmp pairs alias hagg: dead until aggregate writes it, and bucket_build
    // (the last tmp reader) runs before aggregate.
    int2*   tmp      = (int2*)hagg;

    count_wt_kernel<<<512, 256, 0, stream>>>(ei, W, counts, Wtb);
    sscan1_kernel<<<256, 256, 0, stream>>>(counts, blocksum);
    sscan2_kernel<<<1, 256, 0, stream>>>(blocksum, blockbase, gsum, gsumsq);
    sscan3_kernel<<<256, 256, 0, stream>>>(counts, blockbase);
    bucket_scatter_kernel<<<NBLK, 256, 0, stream>>>(ei, counts, tmp);
    bucket_build_kernel<<<NBUCKET, 256, 0, stream>>>(tmp, counts, offsets, csr_src);
    gemm_kernel<<<dim3(2, 391), 256, 0, stream>>>(feature, Wtb, att_src, att_dst, xb, s, dv);
    aggregate_kernel<<<12500, 256, 0, stream>>>(xb, s, dv, offsets, csr_src, hagg);
    bn_stats_kernel<<<BN_BLOCKS, 256, 0, stream>>>(hagg, gsum, gsumsq);
    finalize_kernel<<<3125, 256, 0, stream>>>(feature, hagg, gsum, gsumsq, gamma, beta, out);
}

// Round 6
// 288.581 us; speedup vs baseline: 2.1568x; 1.0203x over previous
//
#include <hip/hip_runtime.h>

#define N_NODES 50000
#define N_EDGES 800000
#define NEG_SLOPE 0.2f
#define BN_EPS  1e-5f

#define CHUNKS 256            // edge chunks for counting sort
#define EDGES_PER_CHUNK 3125  // 256*3125 = 800000 exactly
#define NCOARSE 1024          // coarse buckets = dst>>6
#define NBUCKET 782           // ceil(50000/64) live buckets

typedef short bf16x8 __attribute__((ext_vector_type(8)));
typedef float floatx4 __attribute__((ext_vector_type(4)));

__device__ inline ushort f2bf(float f) {
    union { float f; unsigned u; } v; v.f = f;
    unsigned r = v.u + 0x7fff + ((v.u >> 16) & 1);
    return (ushort)(r >> 16);
}
__device__ inline float bf2f(ushort h) {
    union { unsigned u; float f; } v; v.u = ((unsigned)h) << 16;
    return v.f;
}

// ---------------------------------------------------------------------------
// Pass A + W-transpose fused:
//   blocks [0,256)   : LDS histogram of coarse bucket (dst>>6) over this
//                      block's 3125-edge chunk -> counts[bucket*CHUNKS+chunk]
//   blocks [256,512) : W fp32 [K][N] -> Wt bf16 [N][K]
// ---------------------------------------------------------------------------
__global__ __launch_bounds__(256) void count_wt_kernel(const int* __restrict__ ei,
                                                       const float* __restrict__ W,
                                                       int* __restrict__ counts,
                                                       ushort* __restrict__ Wtb)
{
    __shared__ int hist[NCOARSE];
    const int t = threadIdx.x;
    const int b = blockIdx.x;
    if (b < CHUNKS) {
        for (int j = t; j < NCOARSE; j += 256) hist[j] = 0;
        __syncthreads();
        const int e0 = b * EDGES_PER_CHUNK;
        for (int e = e0 + t; e < e0 + EDGES_PER_CHUNK; e += 256)
            atomicAdd(&hist[ei[N_EDGES + e] >> 6], 1);
        __syncthreads();
        for (int j = t; j < NCOARSE; j += 256)
            counts[j * CHUNKS + b] = hist[j];   // bucket-major for the scan
    } else {
        const int n = b - CHUNKS;               // output col
        Wtb[n * 256 + t] = f2bf(W[t * 256 + n]);
    }
}

// ---------------------------------------------------------------------------
// sscan1 (1024 blocks): block g = bucket g; exclusive scan of its 256
// per-chunk counts in place; blocksum[g] = bucket total.
// ---------------------------------------------------------------------------
__global__ __launch_bounds__(256) void sscan1_kernel(int* __restrict__ counts,
                                                     int* __restrict__ blocksum)
{
    __shared__ int sm[256];
    const int t = threadIdx.x;
    const int i = blockIdx.x * 256 + t;
    const int v = counts[i];
    sm[t] = v;
    __syncthreads();
#pragma unroll
    for (int off = 1; off < 256; off <<= 1) {
        const int u = (t >= off) ? sm[t - off] : 0;
        __syncthreads();
        sm[t] += u;
        __syncthreads();
    }
    counts[i] = sm[t] - v;  // bucket-local exclusive
    if (t == 255) blocksum[blockIdx.x] = sm[255];
}

// ---------------------------------------------------------------------------
// sscan2 (1 block): exclusive scan of blocksum[1024] -> blockbase[1024]
// (global start of each coarse bucket). Also zeros BN accumulators.
// ---------------------------------------------------------------------------
__global__ __launch_bounds__(256) void sscan2_kernel(const int* __restrict__ blocksum,
                                                     int* __restrict__ blockbase,
                                                     float* __restrict__ gsum,
                                                     float* __restrict__ gsumsq)
{
    __shared__ int sm[256];
    const int t = threadIdx.x;
    int v[4], loc[4], tot = 0;
#pragma unroll
    for (int j = 0; j < 4; ++j) {
        v[j] = blocksum[t * 4 + j];
        loc[j] = tot;
        tot += v[j];
    }
    sm[t] = tot;
    __syncthreads();
#pragma unroll
    for (int off = 1; off < 256; off <<= 1) {
        const int u = (t >= off) ? sm[t - off] : 0;
        __syncthreads();
        sm[t] += u;
        __syncthreads();
    }
    const int base = sm[t] - tot;
#pragma unroll
    for (int j = 0; j < 4; ++j) blockbase[t * 4 + j] = base + loc[j];
    gsum[t] = 0.f;
    gsumsq[t] = 0.f;
}

// ---------------------------------------------------------------------------
// Pass B: bucket-partitioned scatter (256 blocks, one per chunk). LDS cursors
// = counts[bucket*CHUNKS+chunk] + blockbase[bucket] (sscan3 folded in).
// tmp packed: (src<<6) | (dst&63). LDS atomics only.
// ---------------------------------------------------------------------------
__global__ __launch_bounds__(256) void bucket_scatter_kernel(const int* __restrict__ ei,
                                                             const int* __restrict__ counts,
                                                             const int* __restrict__ blockbase,
                                                             uint* __restrict__ tmp)
{
    __shared__ int cursor[NCOARSE];
    const int t = threadIdx.x;
    const int blk = blockIdx.x;
    for (int u = t; u < NCOARSE; u += 256)
        cursor[u] = counts[u * CHUNKS + blk] + blockbase[u];
    __syncthreads();
    const int e0 = blk * EDGES_PER_CHUNK;
    for (int e = e0 + t; e < e0 + EDGES_PER_CHUNK; e += 256) {
        const int src = ei[e];
        const int dst = ei[N_EDGES + e];
        const int pos = atomicAdd(&cursor[dst >> 6], 1);
        tmp[pos] = ((uint)src << 6) | (uint)(dst & 63);
    }
}

// ---------------------------------------------------------------------------
// Pass C: per-bucket CSR build (782 blocks, ~1020 edges each):
// LDS 64-bin hist over dst&63 -> LDS scan -> offsets[]; LDS-cursor scatter
// of src into csr_src. LDS atomics only.
// ---------------------------------------------------------------------------
__global__ __launch_bounds__(256) void bucket_build_kernel(const uint* __restrict__ tmp,
                                                           const int* __restrict__ blockbase,
                                                           int* __restrict__ offsets,
                                                           int* __restrict__ csr_src)
{
    __shared__ int hist[64];
    __shared__ int sbuf[64];
    __shared__ int cursor[64];
    const int t = threadIdx.x;
    const int b = blockIdx.x;            // bucket: nodes [b*64, b*64+64)
    const int start = blockbase[b];
    const int end   = blockbase[b + 1];  // buckets >= NBUCKET are empty (==E)
    if (t < 64) hist[t] = 0;
    __syncthreads();
    for (int e = start + t; e < end; e += 256)
        atomicAdd(&hist[tmp[e] & 63], 1);
    __syncthreads();
    const int v = (t < 64) ? hist[t] : 0;
    if (t < 64) sbuf[t] = v;
    __syncthreads();
#pragma unroll
    for (int off = 1; off < 64; off <<= 1) {
        int u = 0;
        if (t < 64 && t >= off) u = sbuf[t - off];
        __syncthreads();
        if (t < 64) sbuf[t] += u;
        __syncthreads();
    }
    if (t < 64) {
        const int excl = start + sbuf[t] - v;
        cursor[t] = excl;
        const int node = b * 64 + t;
        if (node < N_NODES) offsets[node] = excl;
    }
    if (b == 0 && t == 0) offsets[N_NODES] = N_EDGES;
    __syncthreads();
    for (int e = start + t; e < end; e += 256) {
        const uint p = tmp[e];
        const int pos = atomicAdd(&cursor[p & 63], 1);
        csr_src[pos] = (int)(p >> 6);
    }
}

// ---------------------------------------------------------------------------
// MFMA GEMM (fused fp32->bf16 convert of A in staging):
// xb[M,256] = bf16( feature @ W ), 128x128 tile, 4 waves of 64x64.
// Epilogue: per-node attention logits s,d (16-lane shuffle reduce) and
// PERMUTED xb stores: within each 64-col head block, position = l16*4 + ni
// (true col = ni*16 + l16) -> coalesced ushort4 stores.
// ---------------------------------------------------------------------------
#define LDSTRIDE 40  // 32 + 8 pad: 2-way max bank aliasing (free)
__global__ __launch_bounds__(256) void gemm_kernel(const float* __restrict__ A,
                                                   const ushort* __restrict__ Bt,
                                                   const float* __restrict__ att_src,
                                                   const float* __restrict__ att_dst,
                                                   ushort* __restrict__ Xb,
                                                   float* __restrict__ s,
                                                   float* __restrict__ d)
{
    __shared__ ushort As[128 * LDSTRIDE];
    __shared__ ushort Bs[128 * LDSTRIDE];
    const int tid = threadIdx.x;
    const int lane = tid & 63;
    const int wid = tid >> 6;
    const int wm = wid & 1, wn = wid >> 1;
    const int row0 = blockIdx.y * 128;
    const int col0 = blockIdx.x * 128;

    floatx4 acc[4][4] = {};  // [mi][ni]

    const int lr = tid >> 2;        // 0..63 (row base)
    const int lk = (tid & 3) * 8;   // 0,8,16,24 (k elem offset)

    for (int k0 = 0; k0 < 256; k0 += 32) {
#pragma unroll
        for (int r = 0; r < 2; ++r) {
            const int row = lr + r * 64;
            const int grow = row0 + row;
            union { ushort u[8]; ulonglong2 v; } cv;
            if (grow < N_NODES) {
                const float4 f0 = *(const float4*)(A + (size_t)grow * 256 + k0 + lk);
                const float4 f1 = *(const float4*)(A + (size_t)grow * 256 + k0 + lk + 4);
                cv.u[0] = f2bf(f0.x); cv.u[1] = f2bf(f0.y);
                cv.u[2] = f2bf(f0.z); cv.u[3] = f2bf(f0.w);
                cv.u[4] = f2bf(f1.x); cv.u[5] = f2bf(f1.y);
                cv.u[6] = f2bf(f1.z); cv.u[7] = f2bf(f1.w);
            } else {
                cv.v = ulonglong2{0ull, 0ull};
            }
            *(ulonglong2*)(As + row * LDSTRIDE + lk) = cv.v;
            const ulonglong2 bv = *(const ulonglong2*)(Bt + (size_t)(col0 + row) * 256 + k0 + lk);
            *(ulonglong2*)(Bs + row * LDSTRIDE + lk) = bv;
        }
        __syncthreads();
        const int quad = lane >> 4;
        const int l16 = lane & 15;
        bf16x8 afrag[4], bfrag[4];
#pragma unroll
        for (int mi = 0; mi < 4; ++mi)
            afrag[mi] = *(const bf16x8*)(As + (wm * 64 + mi * 16 + l16) * LDSTRIDE + quad * 8);
#pragma unroll
        for (int ni = 0; ni < 4; ++ni)
            bfrag[ni] = *(const bf16x8*)(Bs + (wn * 64 + ni * 16 + l16) * LDSTRIDE + quad * 8);
#pragma unroll
        for (int mi = 0; mi < 4; ++mi)
#pragma unroll
            for (int ni = 0; ni < 4; ++ni)
                acc[mi][ni] = __builtin_amdgcn_mfma_f32_16x16x32_bf16(afrag[mi], bfrag[ni], acc[mi][ni], 0, 0, 0);
        __syncthreads();
    }

    const int quad = lane >> 4;
    const int l16 = lane & 15;
    const int head = (col0 + wn * 64) >> 6;  // wave's 64 cols = one head
    float as_l[4], ad_l[4];
#pragma unroll
    for (int ni = 0; ni < 4; ++ni) {
        const int ch = head * 64 + ni * 16 + l16;  // true channel
        as_l[ni] = att_src[ch];
        ad_l[ni] = att_dst[ch];
    }
#pragma unroll
    for (int mi = 0; mi < 4; ++mi) {
#pragma unroll
        for (int r = 0; r < 4; ++r) {
            const int grow = row0 + wm * 64 + mi * 16 + quad * 4 + r;
            const bool ok = grow < N_NODES;
            float vs = 0.f, vd = 0.f;
            ushort4 o;
#pragma unroll
            for (int ni = 0; ni < 4; ++ni) {
                const float v = acc[mi][ni][r];
                vs += v * as_l[ni];
                vd += v * ad_l[ni];
                ((ushort*)&o)[ni] = f2bf(v);
            }
            if (ok)  // permuted: pos within head block = l16*4 + ni
                *(ushort4*)(Xb + (size_t)grow * 256 + head * 64 + l16 * 4) = o;
#pragma unroll
            for (int m = 8; m >= 1; m >>= 1) {
                vs += __shfl_xor(vs, m);
                vd += __shfl_xor(vd, m);
            }
            if (l16 == 0 && ok) {
                s[grow * 4 + head] = vs;
                d[grow * 4 + head] = vd;
            }
        }
    }
}

// ---------------------------------------------------------------------------
// Aggregate: softmax-weighted gather per dst node (self-loop included).
// One wave per node; lane l owns permuted positions [4l,4l+4); head = l>>4.
// Edge loop unrolled x8 for gather ILP. Output h bf16, permuted layout.
// ---------------------------------------------------------------------------
__global__ __launch_bounds__(256) void aggregate_kernel(const ushort* __restrict__ xb,
                                                        const float* __restrict__ s,
                                                        const float* __restrict__ d,
                                                        const int* __restrict__ offsets,
                                                        const int* __restrict__ csr_src,
                                                        ushort* __restrict__ hagg)
{
    const int wid = threadIdx.x >> 6;
    const int lane = threadIdx.x & 63;
    const int n = blockIdx.x * 4 + wid;
    if (n >= N_NODES) return;
    const int h = lane >> 4;
    const float dn = d[n * 4 + h];
    const float sn = s[n * 4 + h];
    const ushort4 xr = *(const ushort4*)(xb + (size_t)n * 256 + lane * 4);
    float eself = sn + dn;
    eself = eself >= 0.f ? eself : NEG_SLOPE * eself;
    const float pself = __expf(eself);
    float den = pself;
    float a0 = pself * bf2f(xr.x), a1 = pself * bf2f(xr.y);
    float a2 = pself * bf2f(xr.z), a3 = pself * bf2f(xr.w);
    const int e0 = offsets[n];
    const int e1 = offsets[n + 1];
    int e = e0;
    for (; e + 8 <= e1; e += 8) {
        int si[8];
        float lg[8];
        ushort4 xv[8];
#pragma unroll
        for (int j = 0; j < 8; ++j) si[j] = csr_src[e + j];
#pragma unroll
        for (int j = 0; j < 8; ++j) lg[j] = s[si[j] * 4 + h] + dn;
#pragma unroll
        for (int j = 0; j < 8; ++j)
            xv[j] = *(const ushort4*)(xb + (size_t)si[j] * 256 + lane * 4);
#pragma unroll
        for (int j = 0; j < 8; ++j) {
            float l = lg[j];
            l = l >= 0.f ? l : NEG_SLOPE * l;
            const float p = __expf(l);
            den += p;
            a0 += p * bf2f(xv[j].x);
            a1 += p * bf2f(xv[j].y);
            a2 += p * bf2f(xv[j].z);
            a3 += p * bf2f(xv[j].w);
        }
    }
    for (; e < e1; ++e) {
        const int src = csr_src[e];
        float ee = s[src * 4 + h] + dn;
        ee = ee >= 0.f ? ee : NEG_SLOPE * ee;
        const float pe = __expf(ee);
        const ushort4 xs = *(const ushort4*)(xb + (size_t)src * 256 + lane * 4);
        a0 += pe * bf2f(xs.x); a1 += pe * bf2f(xs.y);
        a2 += pe * bf2f(xs.z); a3 += pe * bf2f(xs.w);
        den += pe;
    }
    const float inv = 1.0f / den;
    ushort4 o;
    o.x = f2bf(a0 * inv); o.y = f2bf(a1 * inv);
    o.z = f2bf(a2 * inv); o.w = f2bf(a3 * inv);
    *(ushort4*)(hagg + (size_t)n * 256 + lane * 4) = o;
}

// ---------------------------------------------------------------------------
// BatchNorm stats over bf16 h (permuted channels; bias cancels, ignored).
// ---------------------------------------------------------------------------
#define BN_BLOCKS 784  // 784*64 = 50176 >= 50000
__global__ __launch_bounds__(256) void bn_stats_kernel(const ushort* __restrict__ hagg,
                                                       float* __restrict__ gsum,
                                                       float* __restrict__ gsumsq)
{
    const int c = threadIdx.x;  // permuted channel
    const int r0 = blockIdx.x * 64;
    float sum = 0.f, sq = 0.f;
#pragma unroll 4
    for (int i = 0; i < 64; ++i) {
        const int r = r0 + i;
        if (r < N_NODES) {
            const float v = bf2f(hagg[(size_t)r * 256 + c]);
            sum += v;
            sq += v * v;
        }
    }
    atomicAdd(&gsum[c], sum);
    atomicAdd(&gsumsq[c], sq);
}

// ---------------------------------------------------------------------------
// Finalize (fused bn_final): per-lane computes mean/scale for its 4 permuted
// channels from gsum/gsumsq (L2-resident), then normalize+ELU+residual.
// ---------------------------------------------------------------------------
__global__ __launch_bounds__(256) void finalize_kernel(const float* __restrict__ feature,
                                                       const ushort* __restrict__ hagg,
                                                       const float* __restrict__ gsum,
                                                       const float* __restrict__ gsumsq,
                                                       const float* __restrict__ gamma,
                                                       const float* __restrict__ beta,
                                                       float* __restrict__ out)
{
    const int wid = threadIdx.x >> 6;
    const int lane = threadIdx.x & 63;
    const int wgid = blockIdx.x * 4 + wid;   // 0..12499
    const int hblk = lane >> 4;
    const int l16 = lane & 15;

    float meanv[4], scalev[4], betav[4];
    int tc[4];
#pragma unroll
    for (int j = 0; j < 4; ++j) {
        const int p = lane * 4 + j;                 // permuted channel
        tc[j] = hblk * 64 + j * 16 + l16;           // true channel
        const float m = gsum[p] * (1.0f / N_NODES);
        const float var = gsumsq[p] * (1.0f / N_NODES) - m * m;
        meanv[j] = m;
        scalev[j] = gamma[tc[j]] * rsqrtf(var + BN_EPS);
        betav[j] = beta[tc[j]];
    }
#pragma unroll
    for (int rr = 0; rr < 4; ++rr) {
        const int n = wgid * 4 + rr;
        const ushort4 hv = *(const ushort4*)(hagg + (size_t)n * 256 + lane * 4);
        const float hvf[4] = {bf2f(hv.x), bf2f(hv.y), bf2f(hv.z), bf2f(hv.w)};
#pragma unroll
        for (int j = 0; j < 4; ++j) {
            float r = (hvf[j] - meanv[j]) * scalev[j] + betav[j];
            r = r > 0.f ? r : expm1f(r);
            out[(size_t)n * 256 + tc[j]] = r + feature[(size_t)n * 256 + tc[j]];
        }
    }
}

// ---------------------------------------------------------------------------
extern "C" void kernel_launch(void* const* d_in, const int* in_sizes, int n_in,
                              void* d_out, int out_size, void* d_ws, size_t ws_size,
                              hipStream_t stream)
{
    const float* feature = (const float*)d_in[0];
    const int*   ei      = (const int*)d_in[1];
    const float* W       = (const float*)d_in[2];
    const float* att_src = (const float*)d_in[3];
    const float* att_dst = (const float*)d_in[4];
    // d_in[5] = bias: cancels inside batchnorm, unused
    const float* gamma   = (const float*)d_in[6];
    const float* beta    = (const float*)d_in[7];
    float* out = (float*)d_out;

    char* w = (char*)d_ws;
    auto carve = [&](size_t bytes) {
        char* p = w;
        w += (bytes + 255) & ~(size_t)255;
        return p;
    };
    ushort* Wtb      = (ushort*)carve((size_t)256 * 256 * 2);
    ushort* xb       = (ushort*)carve((size_t)N_NODES * 256 * 2);
    ushort* hagg     = (ushort*)carve((size_t)N_NODES * 256 * 2);
    float*  s        = (float*)carve((size_t)N_NODES * 4 * 4);
    float*  dv       = (float*)carve((size_t)N_NODES * 4 * 4);
    int*    counts   = (int*)carve((size_t)NCOARSE * CHUNKS * 4);  // 1 MB
    int*    offsets  = (int*)carve((size_t)(N_NODES + 1) * 4);
    int*    csr_src  = (int*)carve((size_t)N_EDGES * 4);
    int*    blocksum = (int*)carve((size_t)NCOARSE * 4);
    int*    blockbase= (int*)carve((size_t)NCOARSE * 4);
    float*  gsum     = (float*)carve(256 * 4);
    float*  gsumsq   = (float*)carve(256 * 4);
    // tmp (3.2 MB packed edges) aliases hagg: dead until aggregate writes it;
    // bucket_build (last tmp reader) runs before aggregate.
    uint*   tmp      = (uint*)hagg;

    count_wt_kernel<<<512, 256, 0, stream>>>(ei, W, counts, Wtb);
    sscan1_kernel<<<NCOARSE, 256, 0, stream>>>(counts, blocksum);
    sscan2_kernel<<<1, 256, 0, stream>>>(blocksum, blockbase, gsum, gsumsq);
    bucket_scatter_kernel<<<CHUNKS, 256, 0, stream>>>(ei, counts, blockbase, tmp);
    bucket_build_kernel<<<NBUCKET, 256, 0, stream>>>(tmp, blockbase, offsets, csr_src);
    gemm_kernel<<<dim3(2, 391), 256, 0, stream>>>(feature, Wtb, att_src, att_dst, xb, s, dv);
    aggregate_kernel<<<12500, 256, 0, stream>>>(xb, s, dv, offsets, csr_src, hagg);
    bn_stats_kernel<<<BN_BLOCKS, 256, 0, stream>>>(hagg, gsum, gsumsq);
    finalize_kernel<<<3125, 256, 0, stream>>>(feature, hagg, gsum, gsumsq, gamma, beta, out);
}